// Round 7
// baseline (530.740 us; speedup 1.0000x reference)
//
#include <hip/hip_runtime.h>

// Part_Graph GNN forward on MI355X.
// Inputs: FLOAT32. Output: FLOAT32 (concat):
// [0] xp_new (16,60,3600) | [1] pu_map (16,5,3600) | [2] pl_map (16,3,3600)
// | [3] att_raw (16,16,3600) | [4] ctx_att (16,12,3600)

#define P_TOT 57600
#define RSQEPS 0.99999500003749969f
#define O2 3456000
#define O3 3744000
#define O4 3916800
#define O5 4838400

typedef __attribute__((ext_vector_type(8))) short s8v;
typedef __attribute__((ext_vector_type(4))) float f4v;

__device__ __forceinline__ float bf2f(short s) {
  union { unsigned int i; float f; } u;
  u.i = ((unsigned int)(unsigned short)s) << 16;
  return u.f;
}
__device__ __forceinline__ short f2bf(float f) {
  union { float f; unsigned int i; } u; u.f = f;
  unsigned int r = (u.i + 0x7FFFu + ((u.i >> 16) & 1u)) >> 16;
  return (short)r;
}

// LDS tile index with bank swizzle (same formula for reader and writer).
__device__ __forceinline__ int swz(int m, int c) {
  return m * 256 + (c ^ ((((m >> 3) ^ m) & 7) << 3));
}

// ---------------- K0: MFMA-order weight packing (f32 -> bf16) --------------
#define NW1U 49152
#define NUW  55296
__global__ __launch_bounds__(256) void k0_prep(
    const float* __restrict__ w1, const float* __restrict__ w2,
    short* __restrict__ w1p, short* __restrict__ w2p) {
  int i = blockIdx.x * 256 + threadIdx.x;
  if (i < NW1U) {
    int g = i;
    int lane = g & 63, t1 = g >> 6;
    int kk = t1 & 7, t2 = t1 >> 3;
    int ni = t2 & 3, t3 = t2 >> 2;
    int nblk = t3 & 3, head = t3 >> 2;
    int o = nblk * 64 + ni * 16 + (lane & 15);
    const float* src = w1 + (size_t)head * 65536 + (size_t)o * 256 + kk * 32 + (lane >> 4) * 8;
    short* d = w1p + (size_t)g * 8;
#pragma unroll
    for (int j = 0; j < 8; ++j) d[j] = f2bf(src[j]);
  } else {
    int g = i - NW1U;
    int lane = g & 63, t1 = g >> 6;
    int kk = t1 & 7, t2 = t1 >> 3;
    int f = t2 & 1, head = t2 >> 1;
    int row = f * 16 + (lane & 15);
    short* d = w2p + (size_t)g * 8;
    if (row < 20) {
      const float* src = w2 + (size_t)head * 5120 + (size_t)row * 256 + kk * 32 + (lane >> 4) * 8;
#pragma unroll
      for (int j = 0; j < 8; ++j) d[j] = f2bf(src[j]);
    } else {
#pragma unroll
      for (int j = 0; j < 8; ++j) d[j] = 0;
    }
  }
}

// ---------------- K1: fused proj1 (256->256) + proj2 (256->20), 6 heads ----
__global__ __launch_bounds__(256) void k1_proj(
    const float* __restrict__ xp, const short* __restrict__ w1p,
    const float* __restrict__ g1, const float* __restrict__ b1,
    const short* __restrict__ w2p,
    const float* __restrict__ g2, const float* __restrict__ b2,
    short* __restrict__ ctx) {
  __shared__ short sA[48 * 256];
  __shared__ short sH[48 * 256];
  const int t = threadIdx.x;
  const int p0 = blockIdx.x * 48;         // 48 | 3600 -> never crosses an image
  const int n = p0 / 3600;
  const int hw0 = p0 % 3600;
  const int lane = t & 63;
  const int wid = t >> 6;
  const int l15 = lane & 15;
  const int lg = lane >> 4;

  // stage xp tile (f32 -> bf16): unit u -> (m0=(u%6)*8, c=u/6)
  const float* xpn = xp + (size_t)n * 256 * 3600 + hw0;
#pragma unroll
  for (int it = 0; it < 6; ++it) {
    int u = it * 256 + t;
    int q = u % 6;
    int c = u / 6;
    int m0 = q * 8;
    const float* src = xpn + c * 3600 + m0;
    f4v v0 = *((const f4v*)src);
    f4v v1 = *((const f4v*)(src + 4));
#pragma unroll
    for (int j = 0; j < 4; ++j) {
      sA[swz(m0 + j, c)] = f2bf(v0[j]);
      sA[swz(m0 + 4 + j, c)] = f2bf(v1[j]);
    }
  }
  __syncthreads();

  for (int head = 0; head < 6; ++head) {
    f4v acc[3][4];
#pragma unroll
    for (int mi = 0; mi < 3; ++mi)
#pragma unroll
      for (int ni = 0; ni < 4; ++ni) acc[mi][ni] = (f4v){0.f, 0.f, 0.f, 0.f};
    const int n0 = wid * 64;
    for (int kk = 0; kk < 8; ++kk) {
      s8v a[3], b[4];
#pragma unroll
      for (int mi = 0; mi < 3; ++mi) {
        int m = mi * 16 + l15;
        int c = kk * 32 + lg * 8;
        a[mi] = *((const s8v*)&sA[swz(m, c)]);
      }
#pragma unroll
      for (int ni = 0; ni < 4; ++ni)
        b[ni] = *((const s8v*)(w1p + ((size_t)((((head * 4 + wid) * 4 + ni) * 8 + kk) * 64 + lane)) * 8));
#pragma unroll
      for (int mi = 0; mi < 3; ++mi)
#pragma unroll
        for (int ni = 0; ni < 4; ++ni)
          acc[mi][ni] = __builtin_amdgcn_mfma_f32_16x16x32_bf16(a[mi], b[ni], acc[mi][ni], 0, 0, 0);
    }
    // bn + relu -> sH (bf16).  D layout: row=(lg*4+r), col=l15.
#pragma unroll
    for (int ni = 0; ni < 4; ++ni) {
      int o = n0 + ni * 16 + l15;
      float s = g1[head * 256 + o] * RSQEPS;
      float bb = b1[head * 256 + o];
#pragma unroll
      for (int mi = 0; mi < 3; ++mi)
#pragma unroll
        for (int r = 0; r < 4; ++r) {
          int m = mi * 16 + lg * 4 + r;
          float h = fmaxf(acc[mi][ni][r] * s + bb, 0.f);
          sH[swz(m, o)] = f2bf(h);
        }
    }
    __syncthreads();
    if (wid < 3) {  // GEMM2: wave w owns m-frag w; N=20 padded to 32
      f4v a20 = {0.f, 0.f, 0.f, 0.f}, a21 = {0.f, 0.f, 0.f, 0.f};
      for (int kk = 0; kk < 8; ++kk) {
        int m = wid * 16 + l15;
        int c = kk * 32 + lg * 8;
        s8v av = *((const s8v*)&sH[swz(m, c)]);
        s8v b0 = *((const s8v*)(w2p + ((size_t)(((head * 2 + 0) * 8 + kk) * 64 + lane)) * 8));
        s8v b1v = *((const s8v*)(w2p + ((size_t)(((head * 2 + 1) * 8 + kk) * 64 + lane)) * 8));
        a20 = __builtin_amdgcn_mfma_f32_16x16x32_bf16(av, b0, a20, 0, 0, 0);
        a21 = __builtin_amdgcn_mfma_f32_16x16x32_bf16(av, b1v, a21, 0, 0, 0);
      }
#pragma unroll
      for (int f = 0; f < 2; ++f) {
        int cch = f * 16 + l15;
        if (cch < 20) {
          float s = g2[head * 20 + cch] * RSQEPS;
          float bb = b2[head * 20 + cch];
          short* dst = ctx + (size_t)(head * 20 + cch) * P_TOT + p0;
          f4v& aa = f ? a21 : a20;
#pragma unroll
          for (int r = 0; r < 4; ++r) {
            int m = wid * 16 + lg * 4 + r;
            dst[m] = f2bf(fmaxf(aa[r] * s + bb, 0.f));
          }
        }
      }
    }
    __syncthreads();
  }
}

// ---------------- K2: att_raw / att_soft / ctx_att per pixel ---------------
__global__ __launch_bounds__(256) void k2_att(
    const short* __restrict__ ctx,
    const float* __restrict__ attw, const float* __restrict__ attb,
    const float* __restrict__ ctxw, const float* __restrict__ ctxb,
    float* __restrict__ ws_att, float* __restrict__ out) {
  int p = blockIdx.x * 256 + threadIdx.x;
  int n = p / 3600, hw = p % 3600;
  const int att_off[6] = {0, 2, 5, 8, 11, 14};
#pragma unroll
  for (int i = 0; i < 6; ++i) {
    float fd[10], c0[10];
#pragma unroll
    for (int c = 0; c < 10; ++c) {
      c0[c] = bf2f(ctx[(size_t)(i * 20 + c) * P_TOT + p]);
      fd[c] = bf2f(ctx[(size_t)(i * 20 + 10 + c) * P_TOT + p]);
    }
    const int ci = (i == 0 || i == 5) ? 2 : 3;
    float a[3];
#pragma unroll
    for (int j = 0; j < 3; ++j) {
      if (j < ci) {
        float s = attb[i * 3 + j];
#pragma unroll
        for (int c = 0; c < 10; ++c) s += attw[(i * 3 + j) * 10 + c] * fd[c];
        a[j] = s;
        out[O4 + ((size_t)n * 16 + att_off[i] + j) * 3600 + hw] = s;
      }
    }
    float mx = fmaxf(a[0], a[1]);
    if (ci == 3) mx = fmaxf(mx, a[2]);
    float se = 0.f;
#pragma unroll
    for (int j = 0; j < 3; ++j)
      if (j < ci) { a[j] = __expf(a[j] - mx); se += a[j]; }
    float inv = 1.f / se;
#pragma unroll
    for (int j = 0; j < 3; ++j)
      if (j < ci) ws_att[(size_t)(i * 3 + j) * P_TOT + p] = a[j] * inv;
    float o0 = ctxb[i * 2 + 0];
    float o1 = ctxb[i * 2 + 1];
#pragma unroll
    for (int c = 0; c < 10; ++c) {
      o0 += ctxw[(i * 2 + 0) * 10 + c] * c0[c];
      o1 += ctxw[(i * 2 + 1) * 10 + c] * fd[c];
    }
    out[O5 + ((size_t)n * 12 + i * 2 + 0) * 3600 + hw] = o0;
    out[O5 + ((size_t)n * 12 + i * 2 + 1) * 3600 + hw] = o1;
  }
}

// ---------------- K3: pu/pl maps + softmax gates ---------------------------
__global__ __launch_bounds__(256) void k3_gates(
    const float* __restrict__ xh0, const float* __restrict__ xh1,
    const float* __restrict__ duw, const float* __restrict__ dub,
    const float* __restrict__ dlw, const float* __restrict__ dlb,
    float* __restrict__ ws_pu, float* __restrict__ ws_pl, float* __restrict__ out) {
  int p = blockIdx.x * 256 + threadIdx.x;
  int n = p / 3600, hw = p % 3600;
  float h[10];
#pragma unroll
  for (int c = 0; c < 10; ++c) h[c] = xh0[((size_t)n * 10 + c) * 3600 + hw];
  float a[5];
#pragma unroll
  for (int j = 0; j < 5; ++j) {
    float s = dub[j];
#pragma unroll
    for (int c = 0; c < 10; ++c) s += duw[j * 10 + c] * h[c];
    a[j] = s;
    out[O2 + ((size_t)n * 5 + j) * 3600 + hw] = s;
  }
  float mx = a[0];
#pragma unroll
  for (int j = 1; j < 5; ++j) mx = fmaxf(mx, a[j]);
  float se = 0.f;
#pragma unroll
  for (int j = 0; j < 5; ++j) { a[j] = __expf(a[j] - mx); se += a[j]; }
  float inv = 1.f / se;
#pragma unroll
  for (int j = 0; j < 5; ++j) ws_pu[(size_t)j * P_TOT + p] = a[j] * inv;

#pragma unroll
  for (int c = 0; c < 10; ++c) h[c] = xh1[((size_t)n * 10 + c) * 3600 + hw];
  float b3[3];
#pragma unroll
  for (int j = 0; j < 3; ++j) {
    float s = dlb[j];
#pragma unroll
    for (int c = 0; c < 10; ++c) s += dlw[j * 10 + c] * h[c];
    b3[j] = s;
    out[O3 + ((size_t)n * 3 + j) * 3600 + hw] = s;
  }
  mx = fmaxf(fmaxf(b3[0], b3[1]), b3[2]);
  se = 0.f;
#pragma unroll
  for (int j = 0; j < 3; ++j) { b3[j] = __expf(b3[j] - mx); se += b3[j]; }
  inv = 1.f / se;
#pragma unroll
  for (int j = 0; j < 3; ++j) ws_pl[(size_t)j * P_TOT + p] = b3[j] * inv;
}

// ---------------- K4: decoder + edge messages + GRU, one pixel/thread ------
// Weights staged in LDS; all lanes read the same address (broadcast, no bank
// conflict); compile-time offsets merge into ds_read_b128. Inline tanh keeps
// VGPR pressure low (round-4's tanhf caused 256-VGPR spills).
static __device__ const int INC_N[6] = {1, 2, 2, 2, 2, 1};
static __device__ const int INC_U[6][2] = {{1, 0}, {0, 2}, {1, 3}, {2, 4}, {3, 5}, {4, 0}};
static __device__ const int INC_K[6][2] = {{1, 0}, {1, 1}, {2, 1}, {2, 1}, {2, 1}, {2, 0}};

// LDS layout (floats): 0: c1w[3][400] | 1200: c1s[3][20] | 1260: c1b[3][20]
// | 1320: c2w[3][200] | 1920: c2s[3][10] | 1950: c2b[3][10]
// | 1980: gw[400] | 2380: gb[20] | 2400: cw[200] | 2600: cb[10]  (2610 total)
template <bool ACCUM>
__device__ __forceinline__ void block2_l(
    const float* __restrict__ w1, const float* __restrict__ s1, const float* __restrict__ b1,
    const float* __restrict__ w2, const float* __restrict__ s2, const float* __restrict__ b2,
    const float* __restrict__ ina, const float* __restrict__ inb,
    float* __restrict__ out10) {
  float h[20];
#pragma unroll
  for (int o = 0; o < 20; ++o) {
    float acc = 0.f;
#pragma unroll
    for (int c = 0; c < 10; ++c)
      acc += w1[o * 20 + c] * ina[c] + w1[o * 20 + 10 + c] * inb[c];
    h[o] = fmaxf(acc * s1[o] + b1[o], 0.f);
  }
#pragma unroll
  for (int o = 0; o < 10; ++o) {
    float acc = 0.f;
#pragma unroll
    for (int c = 0; c < 20; ++c) acc += w2[o * 20 + c] * h[c];
    float v = fmaxf(acc * s2[o] + b2[o], 0.f);
    if (ACCUM) out10[o] += v; else out10[o] = v;
  }
}

__global__ __launch_bounds__(256) void k4_node(
    const float* __restrict__ xh0, const float* __restrict__ xh1,
    const float* __restrict__ xp0, const float* __restrict__ xp1,
    const float* __restrict__ xp2, const float* __restrict__ xp3,
    const float* __restrict__ xp4, const float* __restrict__ xp5,
    const float* __restrict__ ws_pu, const float* __restrict__ ws_pl,
    const float* __restrict__ ws_att, const short* __restrict__ ctx,
    const float* __restrict__ c1wg, const float* __restrict__ c1gg, const float* __restrict__ c1bg,
    const float* __restrict__ c2wg, const float* __restrict__ c2gg, const float* __restrict__ c2bg,
    const float* __restrict__ gwg, const float* __restrict__ gbg,
    const float* __restrict__ cwg, const float* __restrict__ cbg,
    float* __restrict__ out) {
  __shared__ float W[2610];
  const int t = threadIdx.x;
  const int node = blockIdx.y;
  for (int u = t; u < 2610; u += 256) {
    float v;
    if (u < 1200) v = c1wg[u];
    else if (u < 1260) v = c1gg[u - 1200] * RSQEPS;
    else if (u < 1320) v = c1bg[u - 1260];
    else if (u < 1920) v = c2wg[u - 1320];
    else if (u < 1950) v = c2gg[u - 1920] * RSQEPS;
    else if (u < 1980) v = c2bg[u - 1950];
    else if (u < 2380) v = gwg[node * 400 + (u - 1980)];
    else if (u < 2400) v = gbg[node * 20 + (u - 2380)];
    else if (u < 2600) v = cwg[node * 200 + (u - 2400)];
    else v = cbg[node * 10 + (u - 2600)];
    W[u] = v;
  }
  __syncthreads();
  const int sdec = (node < 4) ? 0 : 1;
  int p = blockIdx.x * 256 + t;
  int n = p / 3600, hw = p % 3600;
  const float* xhp = (node < 4) ? xh0 : xh1;
  const float* xpl = node == 0 ? xp0 : node == 1 ? xp1 : node == 2 ? xp2
                   : node == 3 ? xp3 : node == 4 ? xp4 : xp5;
  float xpi[10];
#pragma unroll
  for (int c = 0; c < 10; ++c) xpi[c] = xpl[((size_t)n * 10 + c) * 3600 + hw];
  float attg = (node < 4) ? ws_pu[(size_t)(node + 1) * P_TOT + p]
                          : ws_pl[(size_t)(node - 3) * P_TOT + p];
  float gated[10], msg[10];
#pragma unroll
  for (int c = 0; c < 10; ++c)
    gated[c] = xhp[((size_t)n * 10 + c) * 3600 + hw] * attg;
  block2_l<false>(W + sdec * 400, W + 1200 + sdec * 20, W + 1260 + sdec * 20,
                  W + 1320 + sdec * 200, W + 1920 + sdec * 10, W + 1950 + sdec * 10,
                  gated, xpi, msg);
  const int ne = INC_N[node];
  for (int e = 0; e < ne; ++e) {
    int uu = INC_U[node][e], kk = INC_K[node][e];
    float av = ws_att[(size_t)(uu * 3 + kk) * P_TOT + p];
#pragma unroll
    for (int c = 0; c < 10; ++c)
      gated[c] = av * bf2f(ctx[(size_t)(uu * 20 + 10 + c) * P_TOT + p]);
    block2_l<true>(W + 800, W + 1240, W + 1300, W + 1720, W + 1940, W + 1970,
                   gated, xpi, msg);
  }
  // GRU
  float g20[20];
#pragma unroll
  for (int o = 0; o < 20; ++o) {
    float acc = W[2380 + o];
#pragma unroll
    for (int c = 0; c < 10; ++c)
      acc += W[1980 + o * 20 + c] * msg[c] + W[1980 + o * 20 + 10 + c] * xpi[c];
    g20[o] = acc;
  }
  float rh[10];
#pragma unroll
  for (int c = 0; c < 10; ++c) {
    float r = 1.f / (1.f + __expf(-g20[c]));
    rh[c] = r * xpi[c];
  }
#pragma unroll
  for (int o = 0; o < 10; ++o) {
    float acc = W[2600 + o];
#pragma unroll
    for (int c = 0; c < 10; ++c)
      acc += W[2400 + o * 20 + c] * msg[c] + W[2400 + o * 20 + 10 + c] * rh[c];
    // tanh(x) = 1 - 2/(exp(2x)+1), inline, saturating
    float ex = __expf(2.f * acc);
    float cd = 1.f - 2.f / (ex + 1.f);
    float z = 1.f / (1.f + __expf(-g20[10 + o]));
    float res = (1.f - z) * xpi[o] + z * cd;
    out[((size_t)n * 60 + node * 10 + o) * 3600 + hw] = res;
  }
}

// ---------------- launcher -------------------------------------------------
extern "C" void kernel_launch(void* const* d_in, const int* in_sizes, int n_in,
                              void* d_out, int out_size, void* d_ws, size_t ws_size,
                              hipStream_t stream) {
  const float* xh0 = (const float*)d_in[1];
  const float* xh1 = (const float*)d_in[2];
  const float* xp0 = (const float*)d_in[3];
  const float* xp1 = (const float*)d_in[4];
  const float* xp2 = (const float*)d_in[5];
  const float* xp3 = (const float*)d_in[6];
  const float* xp4 = (const float*)d_in[7];
  const float* xp5 = (const float*)d_in[8];
  const float* xp  = (const float*)d_in[9];
  const float* p1w = (const float*)d_in[10];
  const float* p1g = (const float*)d_in[11];
  const float* p1b = (const float*)d_in[12];
  const float* p2w = (const float*)d_in[13];
  const float* p2g = (const float*)d_in[14];
  const float* p2b = (const float*)d_in[15];
  const float* attw = (const float*)d_in[16];
  const float* attb = (const float*)d_in[17];
  const float* ctxw = (const float*)d_in[18];
  const float* ctxb = (const float*)d_in[19];
  const float* duw = (const float*)d_in[20];
  const float* dub = (const float*)d_in[21];
  const float* dlw = (const float*)d_in[22];
  const float* dlb = (const float*)d_in[23];
  const float* c1w = (const float*)d_in[24];
  const float* c1g = (const float*)d_in[25];
  const float* c1b = (const float*)d_in[26];
  const float* c2w = (const float*)d_in[27];
  const float* c2g = (const float*)d_in[28];
  const float* c2b = (const float*)d_in[29];
  const float* gw  = (const float*)d_in[30];
  const float* gb  = (const float*)d_in[31];
  const float* cw  = (const float*)d_in[32];
  const float* cb  = (const float*)d_in[33];

  // Workspace layout (bytes) — total 20,699,136 B (~19.7 MB):
  char* wsb = (char*)d_ws;
  short* w1p   = (short*)(wsb);              //    786,432 B
  short* w2p   = (short*)(wsb + 786432);     //     98,304 B
  short* ctxb2 = (short*)(wsb + 884736);     // 13,824,000 B (bf16 ctx [120][57600])
  float* ws_att = (float*)(wsb + 14708736);  //  4,147,200 B
  float* ws_pu  = (float*)(wsb + 18855936);  //  1,152,000 B
  float* ws_pl  = (float*)(wsb + 20007936);  //    691,200 B
  float* out = (float*)d_out;

  k0_prep<<<216, 256, 0, stream>>>(p1w, p2w, w1p, w2p);
  k1_proj<<<1200, 256, 0, stream>>>(xp, w1p, p1g, p1b, w2p, p2g, p2b, ctxb2);
  k2_att<<<225, 256, 0, stream>>>(ctxb2, attw, attb, ctxw, ctxb, ws_att, out);
  k3_gates<<<225, 256, 0, stream>>>(xh0, xh1, duw, dub, dlw, dlb, ws_pu, ws_pl, out);
  k4_node<<<dim3(225, 6), 256, 0, stream>>>(xh0, xh1, xp0, xp1, xp2, xp3, xp4, xp5,
      ws_pu, ws_pl, ws_att, ctxb2,
      c1w, c1g, c1b, c2w, c2g, c2b, gw, gb, cw, cb, out);
}

// Round 8
// 370.489 us; speedup vs baseline: 1.4325x; 1.4325x over previous
//
#include <hip/hip_runtime.h>

// Part_Graph GNN forward on MI355X.
// Inputs: FLOAT32. Output: FLOAT32 (concat):
// [0] xp_new (16,60,3600) | [1] pu_map (16,5,3600) | [2] pl_map (16,3,3600)
// | [3] att_raw (16,16,3600) | [4] ctx_att (16,12,3600)

#define P_TOT 57600
#define RSQEPS 0.99999500003749969f
#define O2 3456000
#define O3 3744000
#define O4 3916800
#define O5 4838400

typedef __attribute__((ext_vector_type(8))) short s8v;
typedef __attribute__((ext_vector_type(4))) float f4v;

__device__ __forceinline__ float bf2f(short s) {
  union { unsigned int i; float f; } u;
  u.i = ((unsigned int)(unsigned short)s) << 16;
  return u.f;
}
__device__ __forceinline__ short f2bf(float f) {
  union { float f; unsigned int i; } u; u.f = f;
  unsigned int r = (u.i + 0x7FFFu + ((u.i >> 16) & 1u)) >> 16;
  return (short)r;
}

// LDS tile index with bank swizzle (same formula for reader and writer).
__device__ __forceinline__ int swz(int m, int c) {
  return m * 256 + (c ^ ((((m >> 3) ^ m) & 7) << 3));
}

// ---------------- K0: MFMA-order weight packing (f32 -> bf16) --------------
#define NW1U 49152
#define NUW  55296
__global__ __launch_bounds__(256) void k0_prep(
    const float* __restrict__ w1, const float* __restrict__ w2,
    short* __restrict__ w1p, short* __restrict__ w2p) {
  int i = blockIdx.x * 256 + threadIdx.x;
  if (i < NW1U) {
    int g = i;
    int lane = g & 63, t1 = g >> 6;
    int kk = t1 & 7, t2 = t1 >> 3;
    int ni = t2 & 3, t3 = t2 >> 2;
    int nblk = t3 & 3, head = t3 >> 2;
    int o = nblk * 64 + ni * 16 + (lane & 15);
    const float* src = w1 + (size_t)head * 65536 + (size_t)o * 256 + kk * 32 + (lane >> 4) * 8;
    short* d = w1p + (size_t)g * 8;
#pragma unroll
    for (int j = 0; j < 8; ++j) d[j] = f2bf(src[j]);
  } else {
    int g = i - NW1U;
    int lane = g & 63, t1 = g >> 6;
    int kk = t1 & 7, t2 = t1 >> 3;
    int f = t2 & 1, head = t2 >> 1;
    int row = f * 16 + (lane & 15);
    short* d = w2p + (size_t)g * 8;
    if (row < 20) {
      const float* src = w2 + (size_t)head * 5120 + (size_t)row * 256 + kk * 32 + (lane >> 4) * 8;
#pragma unroll
      for (int j = 0; j < 8; ++j) d[j] = f2bf(src[j]);
    } else {
#pragma unroll
      for (int j = 0; j < 8; ++j) d[j] = 0;
    }
  }
}

// ---------------- K1: fused proj1 (256->256) + proj2 (256->20), 6 heads ----
__global__ __launch_bounds__(256) void k1_proj(
    const float* __restrict__ xp, const short* __restrict__ w1p,
    const float* __restrict__ g1, const float* __restrict__ b1,
    const short* __restrict__ w2p,
    const float* __restrict__ g2, const float* __restrict__ b2,
    short* __restrict__ ctx) {
  __shared__ short sA[48 * 256];
  __shared__ short sH[48 * 256];
  const int t = threadIdx.x;
  const int p0 = blockIdx.x * 48;         // 48 | 3600 -> never crosses an image
  const int n = p0 / 3600;
  const int hw0 = p0 % 3600;
  const int lane = t & 63;
  const int wid = t >> 6;
  const int l15 = lane & 15;
  const int lg = lane >> 4;

  // stage xp tile (f32 -> bf16): unit u -> (m0=(u%6)*8, c=u/6)
  const float* xpn = xp + (size_t)n * 256 * 3600 + hw0;
#pragma unroll
  for (int it = 0; it < 6; ++it) {
    int u = it * 256 + t;
    int q = u % 6;
    int c = u / 6;
    int m0 = q * 8;
    const float* src = xpn + c * 3600 + m0;
    f4v v0 = *((const f4v*)src);
    f4v v1 = *((const f4v*)(src + 4));
#pragma unroll
    for (int j = 0; j < 4; ++j) {
      sA[swz(m0 + j, c)] = f2bf(v0[j]);
      sA[swz(m0 + 4 + j, c)] = f2bf(v1[j]);
    }
  }
  __syncthreads();

  for (int head = 0; head < 6; ++head) {
    f4v acc[3][4];
#pragma unroll
    for (int mi = 0; mi < 3; ++mi)
#pragma unroll
      for (int ni = 0; ni < 4; ++ni) acc[mi][ni] = (f4v){0.f, 0.f, 0.f, 0.f};
    const int n0 = wid * 64;
    for (int kk = 0; kk < 8; ++kk) {
      s8v a[3], b[4];
#pragma unroll
      for (int mi = 0; mi < 3; ++mi) {
        int m = mi * 16 + l15;
        int c = kk * 32 + lg * 8;
        a[mi] = *((const s8v*)&sA[swz(m, c)]);
      }
#pragma unroll
      for (int ni = 0; ni < 4; ++ni)
        b[ni] = *((const s8v*)(w1p + ((size_t)((((head * 4 + wid) * 4 + ni) * 8 + kk) * 64 + lane)) * 8));
#pragma unroll
      for (int mi = 0; mi < 3; ++mi)
#pragma unroll
        for (int ni = 0; ni < 4; ++ni)
          acc[mi][ni] = __builtin_amdgcn_mfma_f32_16x16x32_bf16(a[mi], b[ni], acc[mi][ni], 0, 0, 0);
    }
    // bn + relu -> sH (bf16).  D layout: row=(lg*4+r), col=l15.
#pragma unroll
    for (int ni = 0; ni < 4; ++ni) {
      int o = n0 + ni * 16 + l15;
      float s = g1[head * 256 + o] * RSQEPS;
      float bb = b1[head * 256 + o];
#pragma unroll
      for (int mi = 0; mi < 3; ++mi)
#pragma unroll
        for (int r = 0; r < 4; ++r) {
          int m = mi * 16 + lg * 4 + r;
          float h = fmaxf(acc[mi][ni][r] * s + bb, 0.f);
          sH[swz(m, o)] = f2bf(h);
        }
    }
    __syncthreads();
    if (wid < 3) {  // GEMM2: wave w owns m-frag w; N=20 padded to 32
      f4v a20 = {0.f, 0.f, 0.f, 0.f}, a21 = {0.f, 0.f, 0.f, 0.f};
      for (int kk = 0; kk < 8; ++kk) {
        int m = wid * 16 + l15;
        int c = kk * 32 + lg * 8;
        s8v av = *((const s8v*)&sH[swz(m, c)]);
        s8v b0 = *((const s8v*)(w2p + ((size_t)(((head * 2 + 0) * 8 + kk) * 64 + lane)) * 8));
        s8v b1v = *((const s8v*)(w2p + ((size_t)(((head * 2 + 1) * 8 + kk) * 64 + lane)) * 8));
        a20 = __builtin_amdgcn_mfma_f32_16x16x32_bf16(av, b0, a20, 0, 0, 0);
        a21 = __builtin_amdgcn_mfma_f32_16x16x32_bf16(av, b1v, a21, 0, 0, 0);
      }
#pragma unroll
      for (int f = 0; f < 2; ++f) {
        int cch = f * 16 + l15;
        if (cch < 20) {
          float s = g2[head * 20 + cch] * RSQEPS;
          float bb = b2[head * 20 + cch];
          short* dst = ctx + (size_t)(head * 20 + cch) * P_TOT + p0;
          f4v& aa = f ? a21 : a20;
#pragma unroll
          for (int r = 0; r < 4; ++r) {
            int m = wid * 16 + lg * 4 + r;
            dst[m] = f2bf(fmaxf(aa[r] * s + bb, 0.f));
          }
        }
      }
    }
    __syncthreads();
  }
}

// ---------------- K2: att_raw / att_soft / ctx_att per pixel ---------------
__global__ __launch_bounds__(256) void k2_att(
    const short* __restrict__ ctx,
    const float* __restrict__ attw, const float* __restrict__ attb,
    const float* __restrict__ ctxw, const float* __restrict__ ctxb,
    float* __restrict__ ws_att, float* __restrict__ out) {
  int p = blockIdx.x * 256 + threadIdx.x;
  int n = p / 3600, hw = p % 3600;
  const int att_off[6] = {0, 2, 5, 8, 11, 14};
#pragma unroll
  for (int i = 0; i < 6; ++i) {
    float fd[10], c0[10];
#pragma unroll
    for (int c = 0; c < 10; ++c) {
      c0[c] = bf2f(ctx[(size_t)(i * 20 + c) * P_TOT + p]);
      fd[c] = bf2f(ctx[(size_t)(i * 20 + 10 + c) * P_TOT + p]);
    }
    const int ci = (i == 0 || i == 5) ? 2 : 3;
    float a[3];
#pragma unroll
    for (int j = 0; j < 3; ++j) {
      if (j < ci) {
        float s = attb[i * 3 + j];
#pragma unroll
        for (int c = 0; c < 10; ++c) s += attw[(i * 3 + j) * 10 + c] * fd[c];
        a[j] = s;
        out[O4 + ((size_t)n * 16 + att_off[i] + j) * 3600 + hw] = s;
      }
    }
    float mx = fmaxf(a[0], a[1]);
    if (ci == 3) mx = fmaxf(mx, a[2]);
    float se = 0.f;
#pragma unroll
    for (int j = 0; j < 3; ++j)
      if (j < ci) { a[j] = __expf(a[j] - mx); se += a[j]; }
    float inv = 1.f / se;
#pragma unroll
    for (int j = 0; j < 3; ++j)
      if (j < ci) ws_att[(size_t)(i * 3 + j) * P_TOT + p] = a[j] * inv;
    float o0 = ctxb[i * 2 + 0];
    float o1 = ctxb[i * 2 + 1];
#pragma unroll
    for (int c = 0; c < 10; ++c) {
      o0 += ctxw[(i * 2 + 0) * 10 + c] * c0[c];
      o1 += ctxw[(i * 2 + 1) * 10 + c] * fd[c];
    }
    out[O5 + ((size_t)n * 12 + i * 2 + 0) * 3600 + hw] = o0;
    out[O5 + ((size_t)n * 12 + i * 2 + 1) * 3600 + hw] = o1;
  }
}

// ---------------- K3: pu/pl maps + softmax gates ---------------------------
__global__ __launch_bounds__(256) void k3_gates(
    const float* __restrict__ xh0, const float* __restrict__ xh1,
    const float* __restrict__ duw, const float* __restrict__ dub,
    const float* __restrict__ dlw, const float* __restrict__ dlb,
    float* __restrict__ ws_pu, float* __restrict__ ws_pl, float* __restrict__ out) {
  int p = blockIdx.x * 256 + threadIdx.x;
  int n = p / 3600, hw = p % 3600;
  float h[10];
#pragma unroll
  for (int c = 0; c < 10; ++c) h[c] = xh0[((size_t)n * 10 + c) * 3600 + hw];
  float a[5];
#pragma unroll
  for (int j = 0; j < 5; ++j) {
    float s = dub[j];
#pragma unroll
    for (int c = 0; c < 10; ++c) s += duw[j * 10 + c] * h[c];
    a[j] = s;
    out[O2 + ((size_t)n * 5 + j) * 3600 + hw] = s;
  }
  float mx = a[0];
#pragma unroll
  for (int j = 1; j < 5; ++j) mx = fmaxf(mx, a[j]);
  float se = 0.f;
#pragma unroll
  for (int j = 0; j < 5; ++j) { a[j] = __expf(a[j] - mx); se += a[j]; }
  float inv = 1.f / se;
#pragma unroll
  for (int j = 0; j < 5; ++j) ws_pu[(size_t)j * P_TOT + p] = a[j] * inv;

#pragma unroll
  for (int c = 0; c < 10; ++c) h[c] = xh1[((size_t)n * 10 + c) * 3600 + hw];
  float b3[3];
#pragma unroll
  for (int j = 0; j < 3; ++j) {
    float s = dlb[j];
#pragma unroll
    for (int c = 0; c < 10; ++c) s += dlw[j * 10 + c] * h[c];
    b3[j] = s;
    out[O3 + ((size_t)n * 3 + j) * 3600 + hw] = s;
  }
  mx = fmaxf(fmaxf(b3[0], b3[1]), b3[2]);
  se = 0.f;
#pragma unroll
  for (int j = 0; j < 3; ++j) { b3[j] = __expf(b3[j] - mx); se += b3[j]; }
  inv = 1.f / se;
#pragma unroll
  for (int j = 0; j < 3; ++j) ws_pl[(size_t)j * P_TOT + p] = b3[j] * inv;
}

// ---------------- K4: wave-parallel decoder/edges/GRU ----------------------
// Lane layout: 3 groups of 20 lanes per wave (lanes 60-63 idle). Lane j of a
// group holds ROW j of every weight matrix in VGPRs (loaded once, reused over
// 60 pixels). 20-vector state lives one-element-per-lane; matmul row-step =
// fmac(w_row[c], ds_bpermute(in, group_base + c)). No LDS, no per-pixel
// weight traffic, small loop body (I$-friendly).
static __device__ const int INC_N[6] = {1, 2, 2, 2, 2, 1};
static __device__ const int INC_U[6][2] = {{1, 0}, {0, 2}, {1, 3}, {2, 4}, {3, 5}, {4, 0}};
static __device__ const int INC_K[6][2] = {{1, 0}, {1, 1}, {2, 1}, {2, 1}, {2, 1}, {2, 0}};

__device__ __forceinline__ float bcast(float v, int idxbyte) {
  return __int_as_float(__builtin_amdgcn_ds_bpermute(idxbyte, __float_as_int(v)));
}
// 20-wide dot: lane-distributed input `v`, per-lane weight rows `w[20]`.
__device__ __forceinline__ float dot20(const float* __restrict__ w, float v, int baseb) {
  float a0 = 0.f, a1 = 0.f;
#pragma unroll
  for (int c = 0; c < 20; c += 2) {
    a0 += w[c] * bcast(v, baseb + 4 * c);
    a1 += w[c + 1] * bcast(v, baseb + 4 * c + 4);
  }
  return a0 + a1;
}

__global__ __launch_bounds__(256) void k4_node(
    const float* __restrict__ xh0, const float* __restrict__ xh1,
    const float* __restrict__ xp0, const float* __restrict__ xp1,
    const float* __restrict__ xp2, const float* __restrict__ xp3,
    const float* __restrict__ xp4, const float* __restrict__ xp5,
    const float* __restrict__ ws_pu, const float* __restrict__ ws_pl,
    const float* __restrict__ ws_att, const short* __restrict__ ctx,
    const float* __restrict__ c1w, const float* __restrict__ c1g, const float* __restrict__ c1b,
    const float* __restrict__ c2w, const float* __restrict__ c2g, const float* __restrict__ c2b,
    const float* __restrict__ gw, const float* __restrict__ gb,
    const float* __restrict__ cw, const float* __restrict__ cb,
    float* __restrict__ out) {
  const int node = blockIdx.y;
  const int sdec = (node < 4) ? 0 : 1;
  const int lane = threadIdx.x & 63;
  const int wave = threadIdx.x >> 6;
  const int g = lane / 20;           // pixel group 0..2 (3 = idle)
  const int j = lane - g * 20;       // row/channel 0..19
  const int jm = (j < 10) ? j : j - 10;
  const int baseb = (lane - j) * 4;  // bpermute byte base of this group
  const bool lo = (j < 10);

  // ---- distributed weights (row j / jm per lane) ----
  float w1d[20], w1e[20], w2d[20], w2e[20], gwr[20], cwr[20];
#pragma unroll
  for (int c = 0; c < 20; ++c) {
    w1d[c] = c1w[(sdec * 20 + j) * 20 + c];
    w1e[c] = c1w[(40 + j) * 20 + c];
    w2d[c] = c2w[(sdec * 10 + jm) * 20 + c];
    w2e[c] = c2w[(20 + jm) * 20 + c];
    gwr[c] = gw[node * 400 + j * 20 + c];
    cwr[c] = cw[node * 200 + jm * 20 + c];
  }
  const float s1d = c1g[sdec * 20 + j] * RSQEPS, b1d = c1b[sdec * 20 + j];
  const float s1e = c1g[40 + j] * RSQEPS,        b1e = c1b[40 + j];
  const float s2d = c2g[sdec * 10 + jm] * RSQEPS, b2d = c2b[sdec * 10 + jm];
  const float s2e = c2g[20 + jm] * RSQEPS,        b2e = c2b[20 + jm];
  const float gbr = gb[node * 20 + j];
  const float cbr = cb[node * 10 + jm];

  const float* xhp = (node < 4) ? xh0 : xh1;
  const float* xpl = node == 0 ? xp0 : node == 1 ? xp1 : node == 2 ? xp2
                   : node == 3 ? xp3 : node == 4 ? xp4 : xp5;
  const float* gatep = (node < 4) ? ws_pu : ws_pl;
  const int gateidx = (node < 4) ? node + 1 : node - 3;
  const int ne = INC_N[node];
  const int uu0 = INC_U[node][0], kk0 = INC_K[node][0];
  const int uu1 = INC_U[node][1], kk1 = INC_K[node][1];

  const int pxblk = blockIdx.x * 240;          // 240 | 3600 -> one image/block
  const int n = pxblk / 3600;
  const size_t chb = (size_t)(n * 10 + jm) * 3600;   // channel-jm base

  for (int iter = 0; iter < 20; ++iter) {
    int off = wave * 60 + iter * 3 + g;
    int offc = min(off, 239);                  // clamp idle-group overhang
    int px = pxblk + offc;
    int hw = px - n * 3600;
    // per-pixel IO
    float xpv = xpl[chb + hw];                 // xpi[jm]
    float xhv = xhp[chb + hw];                 // xh[jm]
    float attg = gatep[(size_t)gateidx * P_TOT + px];
    // decoder block2: in20 = [xh*att (c<10), xpi (c>=10)]
    float in_r = lo ? xhv * attg : xpv;
    float h_r = fmaxf(dot20(w1d, in_r, baseb) * s1d + b1d, 0.f);
    float msg_r = fmaxf(dot20(w2d, h_r, baseb) * s2d + b2d, 0.f);  // valid j<10
    // edge block2s (set 2), accumulate into msg
    for (int e = 0; e < 2; ++e) {
      if (e >= ne) break;
      int uu = (e == 0) ? uu0 : uu1, kk = (e == 0) ? kk0 : kk1;
      float av = ws_att[(size_t)(uu * 3 + kk) * P_TOT + px];
      float fdv = bf2f(ctx[(size_t)(uu * 20 + 10 + jm) * P_TOT + px]);
      float ein = lo ? av * fdv : xpv;
      float he = fmaxf(dot20(w1e, ein, baseb) * s1e + b1e, 0.f);
      msg_r += fmaxf(dot20(w2e, he, baseb) * s2e + b2e, 0.f);
    }
    // GRU: gates over [msg (c<10), xpi (c>=10)]
    float gin = lo ? msg_r : xpv;
    float g20_r = dot20(gwr, gin, baseb) + gbr;          // gate j at lane j
    float r = 1.f / (1.f + __expf(-g20_r));              // r[j], j<10
    float rh_r = r * xpv;                                // r[j]*xpi[j], j<10
    // cand over [msg (c<10), r*h (c>=10)]: move rh up by 10 lanes
    float rhsh = bcast(rh_r, baseb + 4 * (j - 10));      // garbage for j<10
    float cin = lo ? msg_r : rhsh;
    float ca = dot20(cwr, cin, baseb) + cbr;
    float ex = __expf(2.f * ca);
    float cd = 1.f - 2.f / (ex + 1.f);                   // tanh, j<10
    float zsh = bcast(g20_r, baseb + 4 * (j + 10));      // z-gate j+10 -> lane j
    float z = 1.f / (1.f + __expf(-zsh));
    float res = (1.f - z) * xpv + z * cd;
    if (lo && g < 3)
      out[((size_t)n * 60 + node * 10 + j) * 3600 + hw] = res;
  }
}

// ---------------- launcher -------------------------------------------------
extern "C" void kernel_launch(void* const* d_in, const int* in_sizes, int n_in,
                              void* d_out, int out_size, void* d_ws, size_t ws_size,
                              hipStream_t stream) {
  const float* xh0 = (const float*)d_in[1];
  const float* xh1 = (const float*)d_in[2];
  const float* xp0 = (const float*)d_in[3];
  const float* xp1 = (const float*)d_in[4];
  const float* xp2 = (const float*)d_in[5];
  const float* xp3 = (const float*)d_in[6];
  const float* xp4 = (const float*)d_in[7];
  const float* xp5 = (const float*)d_in[8];
  const float* xp  = (const float*)d_in[9];
  const float* p1w = (const float*)d_in[10];
  const float* p1g = (const float*)d_in[11];
  const float* p1b = (const float*)d_in[12];
  const float* p2w = (const float*)d_in[13];
  const float* p2g = (const float*)d_in[14];
  const float* p2b = (const float*)d_in[15];
  const float* attw = (const float*)d_in[16];
  const float* attb = (const float*)d_in[17];
  const float* ctxw = (const float*)d_in[18];
  const float* ctxb = (const float*)d_in[19];
  const float* duw = (const float*)d_in[20];
  const float* dub = (const float*)d_in[21];
  const float* dlw = (const float*)d_in[22];
  const float* dlb = (const float*)d_in[23];
  const float* c1w = (const float*)d_in[24];
  const float* c1g = (const float*)d_in[25];
  const float* c1b = (const float*)d_in[26];
  const float* c2w = (const float*)d_in[27];
  const float* c2g = (const float*)d_in[28];
  const float* c2b = (const float*)d_in[29];
  const float* gw  = (const float*)d_in[30];
  const float* gb  = (const float*)d_in[31];
  const float* cw  = (const float*)d_in[32];
  const float* cb  = (const float*)d_in[33];

  // Workspace layout (bytes) — total 20,699,136 B (~19.7 MB):
  char* wsb = (char*)d_ws;
  short* w1p   = (short*)(wsb);              //    786,432 B
  short* w2p   = (short*)(wsb + 786432);     //     98,304 B
  short* ctxb2 = (short*)(wsb + 884736);     // 13,824,000 B (bf16 ctx [120][57600])
  float* ws_att = (float*)(wsb + 14708736);  //  4,147,200 B
  float* ws_pu  = (float*)(wsb + 18855936);  //  1,152,000 B
  float* ws_pl  = (float*)(wsb + 20007936);  //    691,200 B
  float* out = (float*)d_out;

  k0_prep<<<216, 256, 0, stream>>>(p1w, p2w, w1p, w2p);
  k1_proj<<<1200, 256, 0, stream>>>(xp, w1p, p1g, p1b, w2p, p2g, p2b, ctxb2);
  k2_att<<<225, 256, 0, stream>>>(ctxb2, attw, attb, ctxw, ctxb, ws_att, out);
  k3_gates<<<225, 256, 0, stream>>>(xh0, xh1, duw, dub, dlw, dlb, ws_pu, ws_pl, out);
  k4_node<<<dim3(240, 6), 256, 0, stream>>>(xh0, xh1, xp0, xp1, xp2, xp3, xp4, xp5,
      ws_pu, ws_pl, ws_att, ctxb2,
      c1w, c1g, c1b, c2w, c2g, c2b, gw, gb, cw, cb, out);
}

// Round 9
// 262.033 us; speedup vs baseline: 2.0255x; 1.4139x over previous
//
#include <hip/hip_runtime.h>

// Part_Graph GNN forward on MI355X.
// Inputs: FLOAT32. Output: FLOAT32 (concat):
// [0] xp_new (16,60,3600) | [1] pu_map (16,5,3600) | [2] pl_map (16,3,3600)
// | [3] att_raw (16,16,3600) | [4] ctx_att (16,12,3600)

#define P_TOT 57600
#define RSQEPS 0.99999500003749969f
#define O2 3456000
#define O3 3744000
#define O4 3916800
#define O5 4838400

typedef __attribute__((ext_vector_type(8))) short s8v;
typedef __attribute__((ext_vector_type(4))) float f4v;

__device__ __forceinline__ float bf2f(short s) {
  union { unsigned int i; float f; } u;
  u.i = ((unsigned int)(unsigned short)s) << 16;
  return u.f;
}
__device__ __forceinline__ short f2bf(float f) {
  union { float f; unsigned int i; } u; u.f = f;
  unsigned int r = (u.i + 0x7FFFu + ((u.i >> 16) & 1u)) >> 16;
  return (short)r;
}

// LDS tile index with bank swizzle (same formula for reader and writer).
__device__ __forceinline__ int swz(int m, int c) {
  return m * 256 + (c ^ ((((m >> 3) ^ m) & 7) << 3));
}

// Anti-hoist fence: stops the scheduler lifting weight ds_reads across matmul
// rows (rounds 4/7 spilled to 256 VGPR + ~500 MB scratch without this).
__device__ __forceinline__ void fence() {
  asm volatile("" ::: "memory");
  __builtin_amdgcn_sched_barrier(0);
}

// ---------------- K0: MFMA-order weight packing (f32 -> bf16) --------------
#define NW1U 49152
#define NUW  55296
__global__ __launch_bounds__(256) void k0_prep(
    const float* __restrict__ w1, const float* __restrict__ w2,
    short* __restrict__ w1p, short* __restrict__ w2p) {
  int i = blockIdx.x * 256 + threadIdx.x;
  if (i < NW1U) {
    int g = i;
    int lane = g & 63, t1 = g >> 6;
    int kk = t1 & 7, t2 = t1 >> 3;
    int ni = t2 & 3, t3 = t2 >> 2;
    int nblk = t3 & 3, head = t3 >> 2;
    int o = nblk * 64 + ni * 16 + (lane & 15);
    const float* src = w1 + (size_t)head * 65536 + (size_t)o * 256 + kk * 32 + (lane >> 4) * 8;
    short* d = w1p + (size_t)g * 8;
#pragma unroll
    for (int j = 0; j < 8; ++j) d[j] = f2bf(src[j]);
  } else {
    int g = i - NW1U;
    int lane = g & 63, t1 = g >> 6;
    int kk = t1 & 7, t2 = t1 >> 3;
    int f = t2 & 1, head = t2 >> 1;
    int row = f * 16 + (lane & 15);
    short* d = w2p + (size_t)g * 8;
    if (row < 20) {
      const float* src = w2 + (size_t)head * 5120 + (size_t)row * 256 + kk * 32 + (lane >> 4) * 8;
#pragma unroll
      for (int j = 0; j < 8; ++j) d[j] = f2bf(src[j]);
    } else {
#pragma unroll
      for (int j = 0; j < 8; ++j) d[j] = 0;
    }
  }
}

// ---------------- K1: fused proj1 (256->256) + proj2 (256->20), 6 heads ----
__global__ __launch_bounds__(256) void k1_proj(
    const float* __restrict__ xp, const short* __restrict__ w1p,
    const float* __restrict__ g1, const float* __restrict__ b1,
    const short* __restrict__ w2p,
    const float* __restrict__ g2, const float* __restrict__ b2,
    short* __restrict__ ctx) {
  __shared__ short sA[48 * 256];
  __shared__ short sH[48 * 256];
  const int t = threadIdx.x;
  const int p0 = blockIdx.x * 48;         // 48 | 3600 -> never crosses an image
  const int n = p0 / 3600;
  const int hw0 = p0 % 3600;
  const int lane = t & 63;
  const int wid = t >> 6;
  const int l15 = lane & 15;
  const int lg = lane >> 4;

  // stage xp tile (f32 -> bf16): unit u -> (m0=(u%6)*8, c=u/6)
  const float* xpn = xp + (size_t)n * 256 * 3600 + hw0;
#pragma unroll
  for (int it = 0; it < 6; ++it) {
    int u = it * 256 + t;
    int q = u % 6;
    int c = u / 6;
    int m0 = q * 8;
    const float* src = xpn + c * 3600 + m0;
    f4v v0 = *((const f4v*)src);
    f4v v1 = *((const f4v*)(src + 4));
#pragma unroll
    for (int j = 0; j < 4; ++j) {
      sA[swz(m0 + j, c)] = f2bf(v0[j]);
      sA[swz(m0 + 4 + j, c)] = f2bf(v1[j]);
    }
  }
  __syncthreads();

  for (int head = 0; head < 6; ++head) {
    f4v acc[3][4];
#pragma unroll
    for (int mi = 0; mi < 3; ++mi)
#pragma unroll
      for (int ni = 0; ni < 4; ++ni) acc[mi][ni] = (f4v){0.f, 0.f, 0.f, 0.f};
    const int n0 = wid * 64;
    for (int kk = 0; kk < 8; ++kk) {
      s8v a[3], b[4];
#pragma unroll
      for (int mi = 0; mi < 3; ++mi) {
        int m = mi * 16 + l15;
        int c = kk * 32 + lg * 8;
        a[mi] = *((const s8v*)&sA[swz(m, c)]);
      }
#pragma unroll
      for (int ni = 0; ni < 4; ++ni)
        b[ni] = *((const s8v*)(w1p + ((size_t)((((head * 4 + wid) * 4 + ni) * 8 + kk) * 64 + lane)) * 8));
#pragma unroll
      for (int mi = 0; mi < 3; ++mi)
#pragma unroll
        for (int ni = 0; ni < 4; ++ni)
          acc[mi][ni] = __builtin_amdgcn_mfma_f32_16x16x32_bf16(a[mi], b[ni], acc[mi][ni], 0, 0, 0);
    }
    // bn + relu -> sH (bf16).  D layout: row=(lg*4+r), col=l15.
#pragma unroll
    for (int ni = 0; ni < 4; ++ni) {
      int o = n0 + ni * 16 + l15;
      float s = g1[head * 256 + o] * RSQEPS;
      float bb = b1[head * 256 + o];
#pragma unroll
      for (int mi = 0; mi < 3; ++mi)
#pragma unroll
        for (int r = 0; r < 4; ++r) {
          int m = mi * 16 + lg * 4 + r;
          float h = fmaxf(acc[mi][ni][r] * s + bb, 0.f);
          sH[swz(m, o)] = f2bf(h);
        }
    }
    __syncthreads();
    if (wid < 3) {  // GEMM2: wave w owns m-frag w; N=20 padded to 32
      f4v a20 = {0.f, 0.f, 0.f, 0.f}, a21 = {0.f, 0.f, 0.f, 0.f};
      for (int kk = 0; kk < 8; ++kk) {
        int m = wid * 16 + l15;
        int c = kk * 32 + lg * 8;
        s8v av = *((const s8v*)&sH[swz(m, c)]);
        s8v b0 = *((const s8v*)(w2p + ((size_t)(((head * 2 + 0) * 8 + kk) * 64 + lane)) * 8));
        s8v b1v = *((const s8v*)(w2p + ((size_t)(((head * 2 + 1) * 8 + kk) * 64 + lane)) * 8));
        a20 = __builtin_amdgcn_mfma_f32_16x16x32_bf16(av, b0, a20, 0, 0, 0);
        a21 = __builtin_amdgcn_mfma_f32_16x16x32_bf16(av, b1v, a21, 0, 0, 0);
      }
#pragma unroll
      for (int f = 0; f < 2; ++f) {
        int cch = f * 16 + l15;
        if (cch < 20) {
          float s = g2[head * 20 + cch] * RSQEPS;
          float bb = b2[head * 20 + cch];
          short* dst = ctx + (size_t)(head * 20 + cch) * P_TOT + p0;
          f4v& aa = f ? a21 : a20;
#pragma unroll
          for (int r = 0; r < 4; ++r) {
            int m = wid * 16 + lg * 4 + r;
            dst[m] = f2bf(fmaxf(aa[r] * s + bb, 0.f));
          }
        }
      }
    }
    __syncthreads();
  }
}

// ---------------- K2: att_raw / att_soft / ctx_att per pixel ---------------
__global__ __launch_bounds__(256) void k2_att(
    const short* __restrict__ ctx,
    const float* __restrict__ attw, const float* __restrict__ attb,
    const float* __restrict__ ctxw, const float* __restrict__ ctxb,
    float* __restrict__ ws_att, float* __restrict__ out) {
  int p = blockIdx.x * 256 + threadIdx.x;
  int n = p / 3600, hw = p % 3600;
  const int att_off[6] = {0, 2, 5, 8, 11, 14};
#pragma unroll
  for (int i = 0; i < 6; ++i) {
    float fd[10], c0[10];
#pragma unroll
    for (int c = 0; c < 10; ++c) {
      c0[c] = bf2f(ctx[(size_t)(i * 20 + c) * P_TOT + p]);
      fd[c] = bf2f(ctx[(size_t)(i * 20 + 10 + c) * P_TOT + p]);
    }
    const int ci = (i == 0 || i == 5) ? 2 : 3;
    float a[3];
#pragma unroll
    for (int j = 0; j < 3; ++j) {
      if (j < ci) {
        float s = attb[i * 3 + j];
#pragma unroll
        for (int c = 0; c < 10; ++c) s += attw[(i * 3 + j) * 10 + c] * fd[c];
        a[j] = s;
        out[O4 + ((size_t)n * 16 + att_off[i] + j) * 3600 + hw] = s;
      }
    }
    float mx = fmaxf(a[0], a[1]);
    if (ci == 3) mx = fmaxf(mx, a[2]);
    float se = 0.f;
#pragma unroll
    for (int j = 0; j < 3; ++j)
      if (j < ci) { a[j] = __expf(a[j] - mx); se += a[j]; }
    float inv = 1.f / se;
#pragma unroll
    for (int j = 0; j < 3; ++j)
      if (j < ci) ws_att[(size_t)(i * 3 + j) * P_TOT + p] = a[j] * inv;
    float o0 = ctxb[i * 2 + 0];
    float o1 = ctxb[i * 2 + 1];
#pragma unroll
    for (int c = 0; c < 10; ++c) {
      o0 += ctxw[(i * 2 + 0) * 10 + c] * c0[c];
      o1 += ctxw[(i * 2 + 1) * 10 + c] * fd[c];
    }
    out[O5 + ((size_t)n * 12 + i * 2 + 0) * 3600 + hw] = o0;
    out[O5 + ((size_t)n * 12 + i * 2 + 1) * 3600 + hw] = o1;
  }
}

// ---------------- K3: pu/pl maps + softmax gates ---------------------------
__global__ __launch_bounds__(256) void k3_gates(
    const float* __restrict__ xh0, const float* __restrict__ xh1,
    const float* __restrict__ duw, const float* __restrict__ dub,
    const float* __restrict__ dlw, const float* __restrict__ dlb,
    float* __restrict__ ws_pu, float* __restrict__ ws_pl, float* __restrict__ out) {
  int p = blockIdx.x * 256 + threadIdx.x;
  int n = p / 3600, hw = p % 3600;
  float h[10];
#pragma unroll
  for (int c = 0; c < 10; ++c) h[c] = xh0[((size_t)n * 10 + c) * 3600 + hw];
  float a[5];
#pragma unroll
  for (int j = 0; j < 5; ++j) {
    float s = dub[j];
#pragma unroll
    for (int c = 0; c < 10; ++c) s += duw[j * 10 + c] * h[c];
    a[j] = s;
    out[O2 + ((size_t)n * 5 + j) * 3600 + hw] = s;
  }
  float mx = a[0];
#pragma unroll
  for (int j = 1; j < 5; ++j) mx = fmaxf(mx, a[j]);
  float se = 0.f;
#pragma unroll
  for (int j = 0; j < 5; ++j) { a[j] = __expf(a[j] - mx); se += a[j]; }
  float inv = 1.f / se;
#pragma unroll
  for (int j = 0; j < 5; ++j) ws_pu[(size_t)j * P_TOT + p] = a[j] * inv;

#pragma unroll
  for (int c = 0; c < 10; ++c) h[c] = xh1[((size_t)n * 10 + c) * 3600 + hw];
  float b3[3];
#pragma unroll
  for (int j = 0; j < 3; ++j) {
    float s = dlb[j];
#pragma unroll
    for (int c = 0; c < 10; ++c) s += dlw[j * 10 + c] * h[c];
    b3[j] = s;
    out[O3 + ((size_t)n * 3 + j) * 3600 + hw] = s;
  }
  mx = fmaxf(fmaxf(b3[0], b3[1]), b3[2]);
  se = 0.f;
#pragma unroll
  for (int j = 0; j < 3; ++j) { b3[j] = __expf(b3[j] - mx); se += b3[j]; }
  inv = 1.f / se;
#pragma unroll
  for (int j = 0; j < 3; ++j) ws_pl[(size_t)j * P_TOT + p] = b3[j] * inv;
}

// ---------------- K4: decoder + edge messages + GRU, one pixel/thread ------
// Weights in LDS (wave-uniform broadcast ds_read_b128, ~550 per wave serving
// 64 pixels vs 3100 bpermutes in the wave-parallel variant). fence() every
// 4 matmul rows stops the scheduler hoisting all weight reads (the round-4/7
// 256-VGPR spill cause). Inline tanh.
static __device__ const int INC_N[6] = {1, 2, 2, 2, 2, 1};
static __device__ const int INC_U[6][2] = {{1, 0}, {0, 2}, {1, 3}, {2, 4}, {3, 5}, {4, 0}};
static __device__ const int INC_K[6][2] = {{1, 0}, {1, 1}, {2, 1}, {2, 1}, {2, 1}, {2, 0}};

// LDS layout (floats): 0: c1w[3][400] | 1200: c1s[3][20] | 1260: c1b[3][20]
// | 1320: c2w[3][200] | 1920: c2s[3][10] | 1950: c2b[3][10]
// | 1980: gw[400] | 2380: gb[20] | 2400: cw[200] | 2600: cb[10]  (2610 total)
template <bool ACCUM>
__device__ __forceinline__ void block2_l(
    const float* __restrict__ w1, const float* __restrict__ s1, const float* __restrict__ b1,
    const float* __restrict__ w2, const float* __restrict__ s2, const float* __restrict__ b2,
    const float* __restrict__ ina, const float* __restrict__ inb,
    float* __restrict__ out10) {
  float h[20];
#pragma unroll
  for (int o = 0; o < 20; ++o) {
    float acc = 0.f;
#pragma unroll
    for (int c = 0; c < 10; ++c)
      acc += w1[o * 20 + c] * ina[c] + w1[o * 20 + 10 + c] * inb[c];
    h[o] = fmaxf(acc * s1[o] + b1[o], 0.f);
    if ((o & 3) == 3) fence();
  }
#pragma unroll
  for (int o = 0; o < 10; ++o) {
    float acc = 0.f;
#pragma unroll
    for (int c = 0; c < 20; ++c) acc += w2[o * 20 + c] * h[c];
    float v = fmaxf(acc * s2[o] + b2[o], 0.f);
    if (ACCUM) out10[o] += v; else out10[o] = v;
    if ((o & 3) == 3) fence();
  }
  fence();
}

__global__ __launch_bounds__(256) void k4_node(
    const float* __restrict__ xh0, const float* __restrict__ xh1,
    const float* __restrict__ xp0, const float* __restrict__ xp1,
    const float* __restrict__ xp2, const float* __restrict__ xp3,
    const float* __restrict__ xp4, const float* __restrict__ xp5,
    const float* __restrict__ ws_pu, const float* __restrict__ ws_pl,
    const float* __restrict__ ws_att, const short* __restrict__ ctx,
    const float* __restrict__ c1wg, const float* __restrict__ c1gg, const float* __restrict__ c1bg,
    const float* __restrict__ c2wg, const float* __restrict__ c2gg, const float* __restrict__ c2bg,
    const float* __restrict__ gwg, const float* __restrict__ gbg,
    const float* __restrict__ cwg, const float* __restrict__ cbg,
    float* __restrict__ out) {
  __shared__ float W[2610];
  const int t = threadIdx.x;
  const int node = blockIdx.y;
  for (int u = t; u < 2610; u += 256) {
    float v;
    if (u < 1200) v = c1wg[u];
    else if (u < 1260) v = c1gg[u - 1200] * RSQEPS;
    else if (u < 1320) v = c1bg[u - 1260];
    else if (u < 1920) v = c2wg[u - 1320];
    else if (u < 1950) v = c2gg[u - 1920] * RSQEPS;
    else if (u < 1980) v = c2bg[u - 1950];
    else if (u < 2380) v = gwg[node * 400 + (u - 1980)];
    else if (u < 2400) v = gbg[node * 20 + (u - 2380)];
    else if (u < 2600) v = cwg[node * 200 + (u - 2400)];
    else v = cbg[node * 10 + (u - 2600)];
    W[u] = v;
  }
  __syncthreads();
  const int sdec = (node < 4) ? 0 : 1;
  int p = blockIdx.x * 256 + t;
  int n = p / 3600, hw = p % 3600;
  const float* xhp = (node < 4) ? xh0 : xh1;
  const float* xpl = node == 0 ? xp0 : node == 1 ? xp1 : node == 2 ? xp2
                   : node == 3 ? xp3 : node == 4 ? xp4 : xp5;
  float xpi[10];
#pragma unroll
  for (int c = 0; c < 10; ++c) xpi[c] = xpl[((size_t)n * 10 + c) * 3600 + hw];
  float attg = (node < 4) ? ws_pu[(size_t)(node + 1) * P_TOT + p]
                          : ws_pl[(size_t)(node - 3) * P_TOT + p];
  float gated[10], msg[10];
#pragma unroll
  for (int c = 0; c < 10; ++c)
    gated[c] = xhp[((size_t)n * 10 + c) * 3600 + hw] * attg;
  fence();
  block2_l<false>(W + sdec * 400, W + 1200 + sdec * 20, W + 1260 + sdec * 20,
                  W + 1320 + sdec * 200, W + 1920 + sdec * 10, W + 1950 + sdec * 10,
                  gated, xpi, msg);
  const int ne = INC_N[node];
#pragma unroll 1
  for (int e = 0; e < ne; ++e) {
    int uu = INC_U[node][e], kk = INC_K[node][e];
    float av = ws_att[(size_t)(uu * 3 + kk) * P_TOT + p];
#pragma unroll
    for (int c = 0; c < 10; ++c)
      gated[c] = av * bf2f(ctx[(size_t)(uu * 20 + 10 + c) * P_TOT + p]);
    fence();
    block2_l<true>(W + 800, W + 1240, W + 1300, W + 1720, W + 1940, W + 1970,
                   gated, xpi, msg);
  }
  // GRU
  float g20[20];
#pragma unroll
  for (int o = 0; o < 20; ++o) {
    float acc = W[2380 + o];
#pragma unroll
    for (int c = 0; c < 10; ++c)
      acc += W[1980 + o * 20 + c] * msg[c] + W[1980 + o * 20 + 10 + c] * xpi[c];
    g20[o] = acc;
    if ((o & 3) == 3) fence();
  }
  float rh[10];
#pragma unroll
  for (int c = 0; c < 10; ++c) {
    float r = 1.f / (1.f + __expf(-g20[c]));
    rh[c] = r * xpi[c];
  }
#pragma unroll
  for (int o = 0; o < 10; ++o) {
    float acc = W[2600 + o];
#pragma unroll
    for (int c = 0; c < 10; ++c)
      acc += W[2400 + o * 20 + c] * msg[c] + W[2400 + o * 20 + 10 + c] * rh[c];
    // tanh(x) = 1 - 2/(exp(2x)+1), inline, saturating
    float ex = __expf(2.f * acc);
    float cd = 1.f - 2.f / (ex + 1.f);
    float z = 1.f / (1.f + __expf(-g20[10 + o]));
    float res = (1.f - z) * xpi[o] + z * cd;
    out[((size_t)n * 60 + node * 10 + o) * 3600 + hw] = res;
    if ((o & 3) == 3) fence();
  }
}

// ---------------- launcher -------------------------------------------------
extern "C" void kernel_launch(void* const* d_in, const int* in_sizes, int n_in,
                              void* d_out, int out_size, void* d_ws, size_t ws_size,
                              hipStream_t stream) {
  const float* xh0 = (const float*)d_in[1];
  const float* xh1 = (const float*)d_in[2];
  const float* xp0 = (const float*)d_in[3];
  const float* xp1 = (const float*)d_in[4];
  const float* xp2 = (const float*)d_in[5];
  const float* xp3 = (const float*)d_in[6];
  const float* xp4 = (const float*)d_in[7];
  const float* xp5 = (const float*)d_in[8];
  const float* xp  = (const float*)d_in[9];
  const float* p1w = (const float*)d_in[10];
  const float* p1g = (const float*)d_in[11];
  const float* p1b = (const float*)d_in[12];
  const float* p2w = (const float*)d_in[13];
  const float* p2g = (const float*)d_in[14];
  const float* p2b = (const float*)d_in[15];
  const float* attw = (const float*)d_in[16];
  const float* attb = (const float*)d_in[17];
  const float* ctxw = (const float*)d_in[18];
  const float* ctxb = (const float*)d_in[19];
  const float* duw = (const float*)d_in[20];
  const float* dub = (const float*)d_in[21];
  const float* dlw = (const float*)d_in[22];
  const float* dlb = (const float*)d_in[23];
  const float* c1w = (const float*)d_in[24];
  const float* c1g = (const float*)d_in[25];
  const float* c1b = (const float*)d_in[26];
  const float* c2w = (const float*)d_in[27];
  const float* c2g = (const float*)d_in[28];
  const float* c2b = (const float*)d_in[29];
  const float* gw  = (const float*)d_in[30];
  const float* gb  = (const float*)d_in[31];
  const float* cw  = (const float*)d_in[32];
  const float* cb  = (const float*)d_in[33];

  // Workspace layout (bytes) — total 20,699,136 B (~19.7 MB):
  char* wsb = (char*)d_ws;
  short* w1p   = (short*)(wsb);              //    786,432 B
  short* w2p   = (short*)(wsb + 786432);     //     98,304 B
  short* ctxb2 = (short*)(wsb + 884736);     // 13,824,000 B (bf16 ctx [120][57600])
  float* ws_att = (float*)(wsb + 14708736);  //  4,147,200 B
  float* ws_pu  = (float*)(wsb + 18855936);  //  1,152,000 B
  float* ws_pl  = (float*)(wsb + 20007936);  //    691,200 B
  float* out = (float*)d_out;

  k0_prep<<<216, 256, 0, stream>>>(p1w, p2w, w1p, w2p);
  k1_proj<<<1200, 256, 0, stream>>>(xp, w1p, p1g, p1b, w2p, p2g, p2b, ctxb2);
  k2_att<<<225, 256, 0, stream>>>(ctxb2, attw, attb, ctxw, ctxb, ws_att, out);
  k3_gates<<<225, 256, 0, stream>>>(xh0, xh1, duw, dub, dlw, dlb, ws_pu, ws_pl, out);
  k4_node<<<dim3(225, 6), 256, 0, stream>>>(xh0, xh1, xp0, xp1, xp2, xp3, xp4, xp5,
      ws_pu, ws_pl, ws_att, ctxb2,
      c1w, c1g, c1b, c2w, c2g, c2b, gw, gb, cw, cb, out);
}

// Round 10
// 244.197 us; speedup vs baseline: 2.1734x; 1.0730x over previous
//
#include <hip/hip_runtime.h>

// Part_Graph GNN forward on MI355X.
// Inputs: FLOAT32. Output: FLOAT32 (concat):
// [0] xp_new (16,60,3600) | [1] pu_map (16,5,3600) | [2] pl_map (16,3,3600)
// | [3] att_raw (16,16,3600) | [4] ctx_att (16,12,3600)

#define P_TOT 57600
#define RSQEPS 0.99999500003749969f
#define O2 3456000
#define O3 3744000
#define O4 3916800
#define O5 4838400

typedef __attribute__((ext_vector_type(8))) short s8v;
typedef __attribute__((ext_vector_type(4))) short s4v;
typedef __attribute__((ext_vector_type(4))) float f4v;

__device__ __forceinline__ float bf2f(short s) {
  union { unsigned int i; float f; } u;
  u.i = ((unsigned int)(unsigned short)s) << 16;
  return u.f;
}
__device__ __forceinline__ short f2bf(float f) {
  union { float f; unsigned int i; } u; u.f = f;
  unsigned int r = (u.i + 0x7FFFu + ((u.i >> 16) & 1u)) >> 16;
  return (short)r;
}

// LDS tile index with bank swizzle (same formula for reader and writer).
// XOR of multiples of 8 preserves 4- and 8-element alignment (b64/b128 ok).
__device__ __forceinline__ int swz(int m, int c) {
  return m * 256 + (c ^ ((((m >> 3) ^ m) & 7) << 3));
}

// Anti-hoist fence: stops the scheduler lifting weight ds_reads across matmul
// rows (k4 rounds 4/7 spilled to 256 VGPR + ~500 MB scratch without this).
__device__ __forceinline__ void fence() {
  asm volatile("" ::: "memory");
  __builtin_amdgcn_sched_barrier(0);
}

// ---------------- K0: MFMA-order weight packing (f32 -> bf16) --------------
#define NW1U 49152
#define NUW  55296
__global__ __launch_bounds__(256) void k0_prep(
    const float* __restrict__ w1, const float* __restrict__ w2,
    short* __restrict__ w1p, short* __restrict__ w2p) {
  int i = blockIdx.x * 256 + threadIdx.x;
  if (i < NW1U) {
    int g = i;
    int lane = g & 63, t1 = g >> 6;
    int kk = t1 & 7, t2 = t1 >> 3;
    int ni = t2 & 3, t3 = t2 >> 2;
    int nblk = t3 & 3, head = t3 >> 2;
    int o = nblk * 64 + ni * 16 + (lane & 15);
    const float* src = w1 + (size_t)head * 65536 + (size_t)o * 256 + kk * 32 + (lane >> 4) * 8;
    short* d = w1p + (size_t)g * 8;
#pragma unroll
    for (int j = 0; j < 8; ++j) d[j] = f2bf(src[j]);
  } else {
    int g = i - NW1U;
    int lane = g & 63, t1 = g >> 6;
    int kk = t1 & 7, t2 = t1 >> 3;
    int f = t2 & 1, head = t2 >> 1;
    int row = f * 16 + (lane & 15);
    short* d = w2p + (size_t)g * 8;
    if (row < 20) {
      const float* src = w2 + (size_t)head * 5120 + (size_t)row * 256 + kk * 32 + (lane >> 4) * 8;
#pragma unroll
      for (int j = 0; j < 8; ++j) d[j] = f2bf(src[j]);
    } else {
#pragma unroll
      for (int j = 0; j < 8; ++j) d[j] = 0;
    }
  }
}

// ---------------- K1: fused proj1 + proj2, TRANSPOSED GEMMs ----------------
// D = W·X^T: A-frag = weight rows (w1p/w2p, packing unchanged — lane l15 =
// row serves A exactly as it served B), B-frag = pixel columns from LDS
// (same b128 reads). D: row = out-channel, col = pixel -> each lane holds 4
// CONSECUTIVE out-channels at one pixel -> sH write is one ds_write_b64
// (12/wave/head vs 48 scalar b16 before; the round-9 3.46M bank-conflict fix).
__global__ __launch_bounds__(256) void k1_proj(
    const float* __restrict__ xp, const short* __restrict__ w1p,
    const float* __restrict__ g1, const float* __restrict__ b1,
    const short* __restrict__ w2p,
    const float* __restrict__ g2, const float* __restrict__ b2,
    short* __restrict__ ctx) {
  __shared__ __align__(16) short sA[48 * 256];
  __shared__ __align__(16) short sH[48 * 256];
  const int t = threadIdx.x;
  const int p0 = blockIdx.x * 48;         // 48 | 3600 -> never crosses an image
  const int n = p0 / 3600;
  const int hw0 = p0 % 3600;
  const int lane = t & 63;
  const int wid = t >> 6;
  const int l15 = lane & 15;
  const int lg = lane >> 4;

  // stage xp tile (f32 -> bf16): unit u -> (m0=(u%6)*8, c=u/6)
  const float* xpn = xp + (size_t)n * 256 * 3600 + hw0;
#pragma unroll
  for (int it = 0; it < 6; ++it) {
    int u = it * 256 + t;
    int q = u % 6;
    int c = u / 6;
    int m0 = q * 8;
    const float* src = xpn + c * 3600 + m0;
    f4v v0 = *((const f4v*)src);
    f4v v1 = *((const f4v*)(src + 4));
#pragma unroll
    for (int j = 0; j < 4; ++j) {
      sA[swz(m0 + j, c)] = f2bf(v0[j]);
      sA[swz(m0 + 4 + j, c)] = f2bf(v1[j]);
    }
  }
  __syncthreads();

  for (int head = 0; head < 6; ++head) {
    f4v acc[4][3];
#pragma unroll
    for (int mi = 0; mi < 4; ++mi)
#pragma unroll
      for (int nf = 0; nf < 3; ++nf) acc[mi][nf] = (f4v){0.f, 0.f, 0.f, 0.f};
    const int n0 = wid * 64;
    for (int kk = 0; kk < 8; ++kk) {
      s8v aW[4], bP[3];
#pragma unroll
      for (int nf = 0; nf < 3; ++nf)
        bP[nf] = *((const s8v*)&sA[swz(nf * 16 + l15, kk * 32 + lg * 8)]);
#pragma unroll
      for (int mi = 0; mi < 4; ++mi)
        aW[mi] = *((const s8v*)(w1p + ((size_t)((((head * 4 + wid) * 4 + mi) * 8 + kk) * 64 + lane)) * 8));
#pragma unroll
      for (int mi = 0; mi < 4; ++mi)
#pragma unroll
        for (int nf = 0; nf < 3; ++nf)
          acc[mi][nf] = __builtin_amdgcn_mfma_f32_16x16x32_bf16(aW[mi], bP[nf], acc[mi][nf], 0, 0, 0);
    }
    // bn + relu -> sH. D: row = out-ch = n0+mi*16+lg*4+r, col = pixel = nf*16+l15.
#pragma unroll
    for (int mi = 0; mi < 4; ++mi) {
      int o4 = n0 + mi * 16 + lg * 4;      // 4 consecutive out-channels
      f4v s4 = *((const f4v*)(g1 + head * 256 + o4));
      f4v c4 = *((const f4v*)(b1 + head * 256 + o4));
#pragma unroll
      for (int nf = 0; nf < 3; ++nf) {
        int pix = nf * 16 + l15;
        s4v pk;
#pragma unroll
        for (int r = 0; r < 4; ++r)
          pk[r] = f2bf(fmaxf(acc[mi][nf][r] * (s4[r] * RSQEPS) + c4[r], 0.f));
        *((s4v*)&sH[swz(pix, o4)]) = pk;   // one ds_write_b64
      }
    }
    __syncthreads();
    if (wid < 3) {  // GEMM2 (transposed): wave w owns pixel-frag w
      f4v a20 = {0.f, 0.f, 0.f, 0.f}, a21 = {0.f, 0.f, 0.f, 0.f};
      for (int kk = 0; kk < 8; ++kk) {
        s8v bH = *((const s8v*)&sH[swz(wid * 16 + l15, kk * 32 + lg * 8)]);
        s8v w20 = *((const s8v*)(w2p + ((size_t)(((head * 2 + 0) * 8 + kk) * 64 + lane)) * 8));
        s8v w21 = *((const s8v*)(w2p + ((size_t)(((head * 2 + 1) * 8 + kk) * 64 + lane)) * 8));
        a20 = __builtin_amdgcn_mfma_f32_16x16x32_bf16(w20, bH, a20, 0, 0, 0);
        a21 = __builtin_amdgcn_mfma_f32_16x16x32_bf16(w21, bH, a21, 0, 0, 0);
      }
      // D: row = out2-ch = mf*16+lg*4+r (valid <20), col = pixel = wid*16+l15
#pragma unroll
      for (int mf = 0; mf < 2; ++mf) {
        int ch4 = mf * 16 + lg * 4;
        if (ch4 < 20) {                    // mf=1: only lg==0 (ch 16..19)
          f4v s4 = *((const f4v*)(g2 + head * 20 + ch4));
          f4v c4 = *((const f4v*)(b2 + head * 20 + ch4));
          f4v& aa = mf ? a21 : a20;
#pragma unroll
          for (int r = 0; r < 4; ++r) {
            float v = fmaxf(aa[r] * (s4[r] * RSQEPS) + c4[r], 0.f);
            ctx[(size_t)(head * 20 + ch4 + r) * P_TOT + p0 + wid * 16 + l15] = f2bf(v);
          }
        }
      }
    }
    __syncthreads();
  }
}

// ---------------- K2: att_raw / att_soft / ctx_att per pixel ---------------
__global__ __launch_bounds__(256) void k2_att(
    const short* __restrict__ ctx,
    const float* __restrict__ attw, const float* __restrict__ attb,
    const float* __restrict__ ctxw, const float* __restrict__ ctxb,
    float* __restrict__ ws_att, float* __restrict__ out) {
  int p = blockIdx.x * 256 + threadIdx.x;
  int n = p / 3600, hw = p % 3600;
  const int att_off[6] = {0, 2, 5, 8, 11, 14};
#pragma unroll
  for (int i = 0; i < 6; ++i) {
    float fd[10], c0[10];
#pragma unroll
    for (int c = 0; c < 10; ++c) {
      c0[c] = bf2f(ctx[(size_t)(i * 20 + c) * P_TOT + p]);
      fd[c] = bf2f(ctx[(size_t)(i * 20 + 10 + c) * P_TOT + p]);
    }
    const int ci = (i == 0 || i == 5) ? 2 : 3;
    float a[3];
#pragma unroll
    for (int j = 0; j < 3; ++j) {
      if (j < ci) {
        float s = attb[i * 3 + j];
#pragma unroll
        for (int c = 0; c < 10; ++c) s += attw[(i * 3 + j) * 10 + c] * fd[c];
        a[j] = s;
        out[O4 + ((size_t)n * 16 + att_off[i] + j) * 3600 + hw] = s;
      }
    }
    float mx = fmaxf(a[0], a[1]);
    if (ci == 3) mx = fmaxf(mx, a[2]);
    float se = 0.f;
#pragma unroll
    for (int j = 0; j < 3; ++j)
      if (j < ci) { a[j] = __expf(a[j] - mx); se += a[j]; }
    float inv = 1.f / se;
#pragma unroll
    for (int j = 0; j < 3; ++j)
      if (j < ci) ws_att[(size_t)(i * 3 + j) * P_TOT + p] = a[j] * inv;
    float o0 = ctxb[i * 2 + 0];
    float o1 = ctxb[i * 2 + 1];
#pragma unroll
    for (int c = 0; c < 10; ++c) {
      o0 += ctxw[(i * 2 + 0) * 10 + c] * c0[c];
      o1 += ctxw[(i * 2 + 1) * 10 + c] * fd[c];
    }
    out[O5 + ((size_t)n * 12 + i * 2 + 0) * 3600 + hw] = o0;
    out[O5 + ((size_t)n * 12 + i * 2 + 1) * 3600 + hw] = o1;
  }
}

// ---------------- K3: pu/pl maps + softmax gates ---------------------------
__global__ __launch_bounds__(256) void k3_gates(
    const float* __restrict__ xh0, const float* __restrict__ xh1,
    const float* __restrict__ duw, const float* __restrict__ dub,
    const float* __restrict__ dlw, const float* __restrict__ dlb,
    float* __restrict__ ws_pu, float* __restrict__ ws_pl, float* __restrict__ out) {
  int p = blockIdx.x * 256 + threadIdx.x;
  int n = p / 3600, hw = p % 3600;
  float h[10];
#pragma unroll
  for (int c = 0; c < 10; ++c) h[c] = xh0[((size_t)n * 10 + c) * 3600 + hw];
  float a[5];
#pragma unroll
  for (int j = 0; j < 5; ++j) {
    float s = dub[j];
#pragma unroll
    for (int c = 0; c < 10; ++c) s += duw[j * 10 + c] * h[c];
    a[j] = s;
    out[O2 + ((size_t)n * 5 + j) * 3600 + hw] = s;
  }
  float mx = a[0];
#pragma unroll
  for (int j = 1; j < 5; ++j) mx = fmaxf(mx, a[j]);
  float se = 0.f;
#pragma unroll
  for (int j = 0; j < 5; ++j) { a[j] = __expf(a[j] - mx); se += a[j]; }
  float inv = 1.f / se;
#pragma unroll
  for (int j = 0; j < 5; ++j) ws_pu[(size_t)j * P_TOT + p] = a[j] * inv;

#pragma unroll
  for (int c = 0; c < 10; ++c) h[c] = xh1[((size_t)n * 10 + c) * 3600 + hw];
  float b3[3];
#pragma unroll
  for (int j = 0; j < 3; ++j) {
    float s = dlb[j];
#pragma unroll
    for (int c = 0; c < 10; ++c) s += dlw[j * 10 + c] * h[c];
    b3[j] = s;
    out[O3 + ((size_t)n * 3 + j) * 3600 + hw] = s;
  }
  mx = fmaxf(fmaxf(b3[0], b3[1]), b3[2]);
  se = 0.f;
#pragma unroll
  for (int j = 0; j < 3; ++j) { b3[j] = __expf(b3[j] - mx); se += b3[j]; }
  inv = 1.f / se;
#pragma unroll
  for (int j = 0; j < 3; ++j) ws_pl[(size_t)j * P_TOT + p] = b3[j] * inv;
}

// ---------------- K4: decoder + edge messages + GRU, one pixel/thread ------
static __device__ const int INC_N[6] = {1, 2, 2, 2, 2, 1};
static __device__ const int INC_U[6][2] = {{1, 0}, {0, 2}, {1, 3}, {2, 4}, {3, 5}, {4, 0}};
static __device__ const int INC_K[6][2] = {{1, 0}, {1, 1}, {2, 1}, {2, 1}, {2, 1}, {2, 0}};

// LDS layout (floats): 0: c1w[3][400] | 1200: c1s[3][20] | 1260: c1b[3][20]
// | 1320: c2w[3][200] | 1920: c2s[3][10] | 1950: c2b[3][10]
// | 1980: gw[400] | 2380: gb[20] | 2400: cw[200] | 2600: cb[10]  (2610 total)
template <bool ACCUM>
__device__ __forceinline__ void block2_l(
    const float* __restrict__ w1, const float* __restrict__ s1, const float* __restrict__ b1,
    const float* __restrict__ w2, const float* __restrict__ s2, const float* __restrict__ b2,
    const float* __restrict__ ina, const float* __restrict__ inb,
    float* __restrict__ out10) {
  float h[20];
#pragma unroll
  for (int o = 0; o < 20; ++o) {
    float acc = 0.f;
#pragma unroll
    for (int c = 0; c < 10; ++c)
      acc += w1[o * 20 + c] * ina[c] + w1[o * 20 + 10 + c] * inb[c];
    h[o] = fmaxf(acc * s1[o] + b1[o], 0.f);
    if ((o & 3) == 3) fence();
  }
#pragma unroll
  for (int o = 0; o < 10; ++o) {
    float acc = 0.f;
#pragma unroll
    for (int c = 0; c < 20; ++c) acc += w2[o * 20 + c] * h[c];
    float v = fmaxf(acc * s2[o] + b2[o], 0.f);
    if (ACCUM) out10[o] += v; else out10[o] = v;
    if ((o & 3) == 3) fence();
  }
  fence();
}

__global__ __launch_bounds__(256) void k4_node(
    const float* __restrict__ xh0, const float* __restrict__ xh1,
    const float* __restrict__ xp0, const float* __restrict__ xp1,
    const float* __restrict__ xp2, const float* __restrict__ xp3,
    const float* __restrict__ xp4, const float* __restrict__ xp5,
    const float* __restrict__ ws_pu, const float* __restrict__ ws_pl,
    const float* __restrict__ ws_att, const short* __restrict__ ctx,
    const float* __restrict__ c1wg, const float* __restrict__ c1gg, const float* __restrict__ c1bg,
    const float* __restrict__ c2wg, const float* __restrict__ c2gg, const float* __restrict__ c2bg,
    const float* __restrict__ gwg, const float* __restrict__ gbg,
    const float* __restrict__ cwg, const float* __restrict__ cbg,
    float* __restrict__ out) {
  __shared__ float W[2610];
  const int t = threadIdx.x;
  const int node = blockIdx.y;
  for (int u = t; u < 2610; u += 256) {
    float v;
    if (u < 1200) v = c1wg[u];
    else if (u < 1260) v = c1gg[u - 1200] * RSQEPS;
    else if (u < 1320) v = c1bg[u - 1260];
    else if (u < 1920) v = c2wg[u - 1320];
    else if (u < 1950) v = c2gg[u - 1920] * RSQEPS;
    else if (u < 1980) v = c2bg[u - 1950];
    else if (u < 2380) v = gwg[node * 400 + (u - 1980)];
    else if (u < 2400) v = gbg[node * 20 + (u - 2380)];
    else if (u < 2600) v = cwg[node * 200 + (u - 2400)];
    else v = cbg[node * 10 + (u - 2600)];
    W[u] = v;
  }
  __syncthreads();
  const int sdec = (node < 4) ? 0 : 1;
  int p = blockIdx.x * 256 + t;
  int n = p / 3600, hw = p % 3600;
  const float* xhp = (node < 4) ? xh0 : xh1;
  const float* xpl = node == 0 ? xp0 : node == 1 ? xp1 : node == 2 ? xp2
                   : node == 3 ? xp3 : node == 4 ? xp4 : xp5;
  float xpi[10];
#pragma unroll
  for (int c = 0; c < 10; ++c) xpi[c] = xpl[((size_t)n * 10 + c) * 3600 + hw];
  float attg = (node < 4) ? ws_pu[(size_t)(node + 1) * P_TOT + p]
                          : ws_pl[(size_t)(node - 3) * P_TOT + p];
  float gated[10], msg[10];
#pragma unroll
  for (int c = 0; c < 10; ++c)
    gated[c] = xhp[((size_t)n * 10 + c) * 3600 + hw] * attg;
  fence();
  block2_l<false>(W + sdec * 400, W + 1200 + sdec * 20, W + 1260 + sdec * 20,
                  W + 1320 + sdec * 200, W + 1920 + sdec * 10, W + 1950 + sdec * 10,
                  gated, xpi, msg);
  const int ne = INC_N[node];
#pragma unroll 1
  for (int e = 0; e < ne; ++e) {
    int uu = INC_U[node][e], kk = INC_K[node][e];
    float av = ws_att[(size_t)(uu * 3 + kk) * P_TOT + p];
#pragma unroll
    for (int c = 0; c < 10; ++c)
      gated[c] = av * bf2f(ctx[(size_t)(uu * 20 + 10 + c) * P_TOT + p]);
    fence();
    block2_l<true>(W + 800, W + 1240, W + 1300, W + 1720, W + 1940, W + 1970,
                   gated, xpi, msg);
  }
  // GRU
  float g20[20];
#pragma unroll
  for (int o = 0; o < 20; ++o) {
    float acc = W[2380 + o];
#pragma unroll
    for (int c = 0; c < 10; ++c)
      acc += W[1980 + o * 20 + c] * msg[c] + W[1980 + o * 20 + 10 + c] * xpi[c];
    g20[o] = acc;
    if ((o & 3) == 3) fence();
  }
  float rh[10];
#pragma unroll
  for (int c = 0; c < 10; ++c) {
    float r = 1.f / (1.f + __expf(-g20[c]));
    rh[c] = r * xpi[c];
  }
#pragma unroll
  for (int o = 0; o < 10; ++o) {
    float acc = W[2600 + o];
#pragma unroll
    for (int c = 0; c < 10; ++c)
      acc += W[2400 + o * 20 + c] * msg[c] + W[2400 + o * 20 + 10 + c] * rh[c];
    // tanh(x) = 1 - 2/(exp(2x)+1), inline, saturating
    float ex = __expf(2.f * acc);
    float cd = 1.f - 2.f / (ex + 1.f);
    float z = 1.f / (1.f + __expf(-g20[10 + o]));
    float res = (1.f - z) * xpi[o] + z * cd;
    out[((size_t)n * 60 + node * 10 + o) * 3600 + hw] = res;
    if ((o & 3) == 3) fence();
  }
}

// ---------------- launcher -------------------------------------------------
extern "C" void kernel_launch(void* const* d_in, const int* in_sizes, int n_in,
                              void* d_out, int out_size, void* d_ws, size_t ws_size,
                              hipStream_t stream) {
  const float* xh0 = (const float*)d_in[1];
  const float* xh1 = (const float*)d_in[2];
  const float* xp0 = (const float*)d_in[3];
  const float* xp1 = (const float*)d_in[4];
  const float* xp2 = (const float*)d_in[5];
  const float* xp3 = (const float*)d_in[6];
  const float* xp4 = (const float*)d_in[7];
  const float* xp5 = (const float*)d_in[8];
  const float* xp  = (const float*)d_in[9];
  const float* p1w = (const float*)d_in[10];
  const float* p1g = (const float*)d_in[11];
  const float* p1b = (const float*)d_in[12];
  const float* p2w = (const float*)d_in[13];
  const float* p2g = (const float*)d_in[14];
  const float* p2b = (const float*)d_in[15];
  const float* attw = (const float*)d_in[16];
  const float* attb = (const float*)d_in[17];
  const float* ctxw = (const float*)d_in[18];
  const float* ctxb = (const float*)d_in[19];
  const float* duw = (const float*)d_in[20];
  const float* dub = (const float*)d_in[21];
  const float* dlw = (const float*)d_in[22];
  const float* dlb = (const float*)d_in[23];
  const float* c1w = (const float*)d_in[24];
  const float* c1g = (const float*)d_in[25];
  const float* c1b = (const float*)d_in[26];
  const float* c2w = (const float*)d_in[27];
  const float* c2g = (const float*)d_in[28];
  const float* c2b = (const float*)d_in[29];
  const float* gw  = (const float*)d_in[30];
  const float* gb  = (const float*)d_in[31];
  const float* cw  = (const float*)d_in[32];
  const float* cb  = (const float*)d_in[33];

  // Workspace layout (bytes) — total 20,699,136 B (~19.7 MB):
  char* wsb = (char*)d_ws;
  short* w1p   = (short*)(wsb);              //    786,432 B
  short* w2p   = (short*)(wsb + 786432);     //     98,304 B
  short* ctxb2 = (short*)(wsb + 884736);     // 13,824,000 B (bf16 ctx [120][57600])
  float* ws_att = (float*)(wsb + 14708736);  //  4,147,200 B
  float* ws_pu  = (float*)(wsb + 18855936);  //  1,152,000 B
  float* ws_pl  = (float*)(wsb + 20007936);  //    691,200 B
  float* out = (float*)d_out;

  k0_prep<<<216, 256, 0, stream>>>(p1w, p2w, w1p, w2p);
  k1_proj<<<1200, 256, 0, stream>>>(xp, w1p, p1g, p1b, w2p, p2g, p2b, ctxb2);
  k2_att<<<225, 256, 0, stream>>>(ctxb2, attw, attb, ctxw, ctxb, ws_att, out);
  k3_gates<<<225, 256, 0, stream>>>(xh0, xh1, duw, dub, dlw, dlb, ws_pu, ws_pl, out);
  k4_node<<<dim3(225, 6), 256, 0, stream>>>(xh0, xh1, xp0, xp1, xp2, xp3, xp4, xp5,
      ws_pu, ws_pl, ws_att, ctxb2,
      c1w, c1g, c1b, c2w, c2g, c2b, gw, gb, cw, cb, out);
}

// Round 11
// 183.547 us; speedup vs baseline: 2.8916x; 1.3304x over previous
//
#include <hip/hip_runtime.h>

// Part_Graph GNN forward on MI355X.
// Inputs: FLOAT32. Output: FLOAT32 (concat):
// [0] xp_new (16,60,3600) | [1] pu_map (16,5,3600) | [2] pl_map (16,3,3600)
// | [3] att_raw (16,16,3600) | [4] ctx_att (16,12,3600)

#define P_TOT 57600
#define RSQEPS 0.99999500003749969f
#define O2 3456000
#define O3 3744000
#define O4 3916800
#define O5 4838400

typedef __attribute__((ext_vector_type(8))) short s8v;
typedef __attribute__((ext_vector_type(4))) short s4v;
typedef __attribute__((ext_vector_type(4))) float f4v;

__device__ __forceinline__ float bf2f(short s) {
  union { unsigned int i; float f; } u;
  u.i = ((unsigned int)(unsigned short)s) << 16;
  return u.f;
}
__device__ __forceinline__ short f2bf(float f) {
  union { float f; unsigned int i; } u; u.f = f;
  unsigned int r = (u.i + 0x7FFFu + ((u.i >> 16) & 1u)) >> 16;
  return (short)r;
}

// LDS tile index with bank swizzle (same formula for reader and writer).
// XOR of multiples of 8 preserves 4- and 8-element alignment (b64/b128 ok).
__device__ __forceinline__ int swz(int m, int c) {
  return m * 256 + (c ^ ((((m >> 3) ^ m) & 7) << 3));
}

// Anti-hoist fence: stops the scheduler lifting weight ds_reads across matmul
// rows (k4 rounds 4/7 spilled to 256 VGPR + ~500 MB scratch without this).
__device__ __forceinline__ void fence() {
  asm volatile("" ::: "memory");
  __builtin_amdgcn_sched_barrier(0);
}

// ---------------- K0: MFMA-order weight packing (f32 -> bf16) --------------
#define NW1U 49152
#define NUW  55296
__global__ __launch_bounds__(256) void k0_prep(
    const float* __restrict__ w1, const float* __restrict__ w2,
    short* __restrict__ w1p, short* __restrict__ w2p) {
  int i = blockIdx.x * 256 + threadIdx.x;
  if (i < NW1U) {
    int g = i;
    int lane = g & 63, t1 = g >> 6;
    int kk = t1 & 7, t2 = t1 >> 3;
    int ni = t2 & 3, t3 = t2 >> 2;
    int nblk = t3 & 3, head = t3 >> 2;
    int o = nblk * 64 + ni * 16 + (lane & 15);
    const float* src = w1 + (size_t)head * 65536 + (size_t)o * 256 + kk * 32 + (lane >> 4) * 8;
    short* d = w1p + (size_t)g * 8;
#pragma unroll
    for (int j = 0; j < 8; ++j) d[j] = f2bf(src[j]);
  } else {
    int g = i - NW1U;
    int lane = g & 63, t1 = g >> 6;
    int kk = t1 & 7, t2 = t1 >> 3;
    int f = t2 & 1, head = t2 >> 1;
    int row = f * 16 + (lane & 15);
    short* d = w2p + (size_t)g * 8;
    if (row < 20) {
      const float* src = w2 + (size_t)head * 5120 + (size_t)row * 256 + kk * 32 + (lane >> 4) * 8;
#pragma unroll
      for (int j = 0; j < 8; ++j) d[j] = f2bf(src[j]);
    } else {
#pragma unroll
      for (int j = 0; j < 8; ++j) d[j] = 0;
    }
  }
}

// ---------------- K1: fused proj1 + proj2, transposed GEMMs ----------------
// D = W·X^T. aW loads are L2-latency-bound (round-10 diagnosis): 2-deep
// register ping-pong prefetch overlaps next-kk loads with current-kk MFMA.
// __launch_bounds__(256,3): VGPR cap ~170 = 3 waves/SIMD, matching the LDS
// 3-block/CU limit, giving the scheduler prefetch headroom (was capped 128).
__global__ __launch_bounds__(256, 3) void k1_proj(
    const float* __restrict__ xp, const short* __restrict__ w1p,
    const float* __restrict__ g1, const float* __restrict__ b1,
    const short* __restrict__ w2p,
    const float* __restrict__ g2, const float* __restrict__ b2,
    short* __restrict__ ctx) {
  __shared__ __align__(16) short sA[48 * 256];
  __shared__ __align__(16) short sH[48 * 256];
  const int t = threadIdx.x;
  const int p0 = blockIdx.x * 48;         // 48 | 3600 -> never crosses an image
  const int n = p0 / 3600;
  const int hw0 = p0 % 3600;
  const int lane = t & 63;
  const int wid = t >> 6;
  const int l15 = lane & 15;
  const int lg = lane >> 4;

  // stage xp tile (f32 -> bf16): unit u -> (m0=(u%6)*8, c=u/6)
  const float* xpn = xp + (size_t)n * 256 * 3600 + hw0;
#pragma unroll
  for (int it = 0; it < 6; ++it) {
    int u = it * 256 + t;
    int q = u % 6;
    int c = u / 6;
    int m0 = q * 8;
    const float* src = xpn + c * 3600 + m0;
    f4v v0 = *((const f4v*)src);
    f4v v1 = *((const f4v*)(src + 4));
#pragma unroll
    for (int j = 0; j < 4; ++j) {
      sA[swz(m0 + j, c)] = f2bf(v0[j]);
      sA[swz(m0 + 4 + j, c)] = f2bf(v1[j]);
    }
  }
  __syncthreads();

  for (int head = 0; head < 6; ++head) {
    f4v acc[4][3];
#pragma unroll
    for (int mi = 0; mi < 4; ++mi)
#pragma unroll
      for (int nf = 0; nf < 3; ++nf) acc[mi][nf] = (f4v){0.f, 0.f, 0.f, 0.f};
    const int n0 = wid * 64;
    const short* wb = w1p + (size_t)(head * 4 + wid) * (4 * 8 * 64 * 8);
    s8v aWa[4], aWb[4];
#pragma unroll
    for (int mi = 0; mi < 4; ++mi)
      aWa[mi] = *((const s8v*)(wb + ((mi * 8 + 0) * 64 + lane) * 8));
#pragma unroll
    for (int kk = 0; kk < 8; ++kk) {
      s8v (&cur)[4] = (kk & 1) ? aWb : aWa;
      s8v (&nxt)[4] = (kk & 1) ? aWa : aWb;
      if (kk < 7) {
#pragma unroll
        for (int mi = 0; mi < 4; ++mi)
          nxt[mi] = *((const s8v*)(wb + ((mi * 8 + kk + 1) * 64 + lane) * 8));
      }
      s8v bP[3];
#pragma unroll
      for (int nf = 0; nf < 3; ++nf)
        bP[nf] = *((const s8v*)&sA[swz(nf * 16 + l15, kk * 32 + lg * 8)]);
#pragma unroll
      for (int mi = 0; mi < 4; ++mi)
#pragma unroll
        for (int nf = 0; nf < 3; ++nf)
          acc[mi][nf] = __builtin_amdgcn_mfma_f32_16x16x32_bf16(cur[mi], bP[nf], acc[mi][nf], 0, 0, 0);
    }
    // bn + relu -> sH. D: row = out-ch = n0+mi*16+lg*4+r, col = pixel = nf*16+l15.
#pragma unroll
    for (int mi = 0; mi < 4; ++mi) {
      int o4 = n0 + mi * 16 + lg * 4;      // 4 consecutive out-channels
      f4v s4 = *((const f4v*)(g1 + head * 256 + o4));
      f4v c4 = *((const f4v*)(b1 + head * 256 + o4));
#pragma unroll
      for (int nf = 0; nf < 3; ++nf) {
        int pix = nf * 16 + l15;
        s4v pk;
#pragma unroll
        for (int r = 0; r < 4; ++r)
          pk[r] = f2bf(fmaxf(acc[mi][nf][r] * (s4[r] * RSQEPS) + c4[r], 0.f));
        *((s4v*)&sH[swz(pix, o4)]) = pk;   // one ds_write_b64
      }
    }
    __syncthreads();
    if (wid < 3) {  // GEMM2 (transposed): wave w owns pixel-frag w
      f4v a20 = {0.f, 0.f, 0.f, 0.f}, a21 = {0.f, 0.f, 0.f, 0.f};
#pragma unroll
      for (int kk = 0; kk < 8; ++kk) {
        s8v bH = *((const s8v*)&sH[swz(wid * 16 + l15, kk * 32 + lg * 8)]);
        s8v w20 = *((const s8v*)(w2p + ((size_t)(((head * 2 + 0) * 8 + kk) * 64 + lane)) * 8));
        s8v w21 = *((const s8v*)(w2p + ((size_t)(((head * 2 + 1) * 8 + kk) * 64 + lane)) * 8));
        a20 = __builtin_amdgcn_mfma_f32_16x16x32_bf16(w20, bH, a20, 0, 0, 0);
        a21 = __builtin_amdgcn_mfma_f32_16x16x32_bf16(w21, bH, a21, 0, 0, 0);
      }
      // D: row = out2-ch = mf*16+lg*4+r (valid <20), col = pixel = wid*16+l15
#pragma unroll
      for (int mf = 0; mf < 2; ++mf) {
        int ch4 = mf * 16 + lg * 4;
        if (ch4 < 20) {                    // mf=1: only lg==0 (ch 16..19)
          f4v s4 = *((const f4v*)(g2 + head * 20 + ch4));
          f4v c4 = *((const f4v*)(b2 + head * 20 + ch4));
          f4v& aa = mf ? a21 : a20;
#pragma unroll
          for (int r = 0; r < 4; ++r) {
            float v = fmaxf(aa[r] * (s4[r] * RSQEPS) + c4[r], 0.f);
            ctx[(size_t)(head * 20 + ch4 + r) * P_TOT + p0 + wid * 16 + l15] = f2bf(v);
          }
        }
      }
    }
    __syncthreads();
  }
}

// ---------------- K2: att_raw / att_soft / ctx_att, one head per block.y ---
__global__ __launch_bounds__(256) void k2_att(
    const short* __restrict__ ctx,
    const float* __restrict__ attw, const float* __restrict__ attb,
    const float* __restrict__ ctxw, const float* __restrict__ ctxb,
    float* __restrict__ ws_att, float* __restrict__ out) {
  int p = blockIdx.x * 256 + threadIdx.x;
  const int i = blockIdx.y;
  int n = p / 3600, hw = p % 3600;
  const int att_off[6] = {0, 2, 5, 8, 11, 14};
  float fd[10], c0[10];
#pragma unroll
  for (int c = 0; c < 10; ++c) {
    c0[c] = bf2f(ctx[(size_t)(i * 20 + c) * P_TOT + p]);
    fd[c] = bf2f(ctx[(size_t)(i * 20 + 10 + c) * P_TOT + p]);
  }
  const int ci = (i == 0 || i == 5) ? 2 : 3;
  float a[3];
#pragma unroll
  for (int j = 0; j < 3; ++j) {
    if (j < ci) {
      float s = attb[i * 3 + j];
#pragma unroll
      for (int c = 0; c < 10; ++c) s += attw[(i * 3 + j) * 10 + c] * fd[c];
      a[j] = s;
      out[O4 + ((size_t)n * 16 + att_off[i] + j) * 3600 + hw] = s;
    }
  }
  float mx = fmaxf(a[0], a[1]);
  if (ci == 3) mx = fmaxf(mx, a[2]);
  float se = 0.f;
#pragma unroll
  for (int j = 0; j < 3; ++j)
    if (j < ci) { a[j] = __expf(a[j] - mx); se += a[j]; }
  float inv = 1.f / se;
#pragma unroll
  for (int j = 0; j < 3; ++j)
    if (j < ci) ws_att[(size_t)(i * 3 + j) * P_TOT + p] = a[j] * inv;
  float o0 = ctxb[i * 2 + 0];
  float o1 = ctxb[i * 2 + 1];
#pragma unroll
  for (int c = 0; c < 10; ++c) {
    o0 += ctxw[(i * 2 + 0) * 10 + c] * c0[c];
    o1 += ctxw[(i * 2 + 1) * 10 + c] * fd[c];
  }
  out[O5 + ((size_t)n * 12 + i * 2 + 0) * 3600 + hw] = o0;
  out[O5 + ((size_t)n * 12 + i * 2 + 1) * 3600 + hw] = o1;
}

// ---------------- K3: pu/pl maps + softmax gates (split by block.y) --------
__global__ __launch_bounds__(256) void k3_gates(
    const float* __restrict__ xh0, const float* __restrict__ xh1,
    const float* __restrict__ duw, const float* __restrict__ dub,
    const float* __restrict__ dlw, const float* __restrict__ dlb,
    float* __restrict__ ws_pu, float* __restrict__ ws_pl, float* __restrict__ out) {
  int p = blockIdx.x * 256 + threadIdx.x;
  int n = p / 3600, hw = p % 3600;
  if (blockIdx.y == 0) {
    float h[10];
#pragma unroll
    for (int c = 0; c < 10; ++c) h[c] = xh0[((size_t)n * 10 + c) * 3600 + hw];
    float a[5];
#pragma unroll
    for (int j = 0; j < 5; ++j) {
      float s = dub[j];
#pragma unroll
      for (int c = 0; c < 10; ++c) s += duw[j * 10 + c] * h[c];
      a[j] = s;
      out[O2 + ((size_t)n * 5 + j) * 3600 + hw] = s;
    }
    float mx = a[0];
#pragma unroll
    for (int j = 1; j < 5; ++j) mx = fmaxf(mx, a[j]);
    float se = 0.f;
#pragma unroll
    for (int j = 0; j < 5; ++j) { a[j] = __expf(a[j] - mx); se += a[j]; }
    float inv = 1.f / se;
#pragma unroll
    for (int j = 0; j < 5; ++j) ws_pu[(size_t)j * P_TOT + p] = a[j] * inv;
  } else {
    float h[10];
#pragma unroll
    for (int c = 0; c < 10; ++c) h[c] = xh1[((size_t)n * 10 + c) * 3600 + hw];
    float b3[3];
#pragma unroll
    for (int j = 0; j < 3; ++j) {
      float s = dlb[j];
#pragma unroll
      for (int c = 0; c < 10; ++c) s += dlw[j * 10 + c] * h[c];
      b3[j] = s;
      out[O3 + ((size_t)n * 3 + j) * 3600 + hw] = s;
    }
    float mx = fmaxf(fmaxf(b3[0], b3[1]), b3[2]);
    float se = 0.f;
#pragma unroll
    for (int j = 0; j < 3; ++j) { b3[j] = __expf(b3[j] - mx); se += b3[j]; }
    float inv = 1.f / se;
#pragma unroll
    for (int j = 0; j < 3; ++j) ws_pl[(size_t)j * P_TOT + p] = b3[j] * inv;
  }
}

// ---------------- K4: decoder + edge messages + GRU, one pixel/thread ------
static __device__ const int INC_N[6] = {1, 2, 2, 2, 2, 1};
static __device__ const int INC_U[6][2] = {{1, 0}, {0, 2}, {1, 3}, {2, 4}, {3, 5}, {4, 0}};
static __device__ const int INC_K[6][2] = {{1, 0}, {1, 1}, {2, 1}, {2, 1}, {2, 1}, {2, 0}};

// LDS layout (floats): 0: c1w[3][400] | 1200: c1s[3][20] | 1260: c1b[3][20]
// | 1320: c2w[3][200] | 1920: c2s[3][10] | 1950: c2b[3][10]
// | 1980: gw[400] | 2380: gb[20] | 2400: cw[200] | 2600: cb[10]  (2610 total)
template <bool ACCUM>
__device__ __forceinline__ void block2_l(
    const float* __restrict__ w1, const float* __restrict__ s1, const float* __restrict__ b1,
    const float* __restrict__ w2, const float* __restrict__ s2, const float* __restrict__ b2,
    const float* __restrict__ ina, const float* __restrict__ inb,
    float* __restrict__ out10) {
  float h[20];
#pragma unroll
  for (int o = 0; o < 20; ++o) {
    float acc = 0.f;
#pragma unroll
    for (int c = 0; c < 10; ++c)
      acc += w1[o * 20 + c] * ina[c] + w1[o * 20 + 10 + c] * inb[c];
    h[o] = fmaxf(acc * s1[o] + b1[o], 0.f);
    if ((o & 3) == 3) fence();
  }
#pragma unroll
  for (int o = 0; o < 10; ++o) {
    float acc = 0.f;
#pragma unroll
    for (int c = 0; c < 20; ++c) acc += w2[o * 20 + c] * h[c];
    float v = fmaxf(acc * s2[o] + b2[o], 0.f);
    if (ACCUM) out10[o] += v; else out10[o] = v;
    if ((o & 3) == 3) fence();
  }
  fence();
}

__global__ __launch_bounds__(256) void k4_node(
    const float* __restrict__ xh0, const float* __restrict__ xh1,
    const float* __restrict__ xp0, const float* __restrict__ xp1,
    const float* __restrict__ xp2, const float* __restrict__ xp3,
    const float* __restrict__ xp4, const float* __restrict__ xp5,
    const float* __restrict__ ws_pu, const float* __restrict__ ws_pl,
    const float* __restrict__ ws_att, const short* __restrict__ ctx,
    const float* __restrict__ c1wg, const float* __restrict__ c1gg, const float* __restrict__ c1bg,
    const float* __restrict__ c2wg, const float* __restrict__ c2gg, const float* __restrict__ c2bg,
    const float* __restrict__ gwg, const float* __restrict__ gbg,
    const float* __restrict__ cwg, const float* __restrict__ cbg,
    float* __restrict__ out) {
  __shared__ float W[2610];
  const int t = threadIdx.x;
  const int node = blockIdx.y;
  for (int u = t; u < 2610; u += 256) {
    float v;
    if (u < 1200) v = c1wg[u];
    else if (u < 1260) v = c1gg[u - 1200] * RSQEPS;
    else if (u < 1320) v = c1bg[u - 1260];
    else if (u < 1920) v = c2wg[u - 1320];
    else if (u < 1950) v = c2gg[u - 1920] * RSQEPS;
    else if (u < 1980) v = c2bg[u - 1950];
    else if (u < 2380) v = gwg[node * 400 + (u - 1980)];
    else if (u < 2400) v = gbg[node * 20 + (u - 2380)];
    else if (u < 2600) v = cwg[node * 200 + (u - 2400)];
    else v = cbg[node * 10 + (u - 2600)];
    W[u] = v;
  }
  __syncthreads();
  const int sdec = (node < 4) ? 0 : 1;
  int p = blockIdx.x * 256 + t;
  int n = p / 3600, hw = p % 3600;
  const float* xhp = (node < 4) ? xh0 : xh1;
  const float* xpl = node == 0 ? xp0 : node == 1 ? xp1 : node == 2 ? xp2
                   : node == 3 ? xp3 : node == 4 ? xp4 : xp5;
  float xpi[10];
#pragma unroll
  for (int c = 0; c < 10; ++c) xpi[c] = xpl[((size_t)n * 10 + c) * 3600 + hw];
  float attg = (node < 4) ? ws_pu[(size_t)(node + 1) * P_TOT + p]
                          : ws_pl[(size_t)(node - 3) * P_TOT + p];
  float gated[10], msg[10];
#pragma unroll
  for (int c = 0; c < 10; ++c)
    gated[c] = xhp[((size_t)n * 10 + c) * 3600 + hw] * attg;
  fence();
  block2_l<false>(W + sdec * 400, W + 1200 + sdec * 20, W + 1260 + sdec * 20,
                  W + 1320 + sdec * 200, W + 1920 + sdec * 10, W + 1950 + sdec * 10,
                  gated, xpi, msg);
  const int ne = INC_N[node];
#pragma unroll 1
  for (int e = 0; e < ne; ++e) {
    int uu = INC_U[node][e], kk = INC_K[node][e];
    float av = ws_att[(size_t)(uu * 3 + kk) * P_TOT + p];
#pragma unroll
    for (int c = 0; c < 10; ++c)
      gated[c] = av * bf2f(ctx[(size_t)(uu * 20 + 10 + c) * P_TOT + p]);
    fence();
    block2_l<true>(W + 800, W + 1240, W + 1300, W + 1720, W + 1940, W + 1970,
                   gated, xpi, msg);
  }
  // GRU
  float g20[20];
#pragma unroll
  for (int o = 0; o < 20; ++o) {
    float acc = W[2380 + o];
#pragma unroll
    for (int c = 0; c < 10; ++c)
      acc += W[1980 + o * 20 + c] * msg[c] + W[1980 + o * 20 + 10 + c] * xpi[c];
    g20[o] = acc;
    if ((o & 3) == 3) fence();
  }
  float rh[10];
#pragma unroll
  for (int c = 0; c < 10; ++c) {
    float r = 1.f / (1.f + __expf(-g20[c]));
    rh[c] = r * xpi[c];
  }
#pragma unroll
  for (int o = 0; o < 10; ++o) {
    float acc = W[2600 + o];
#pragma unroll
    for (int c = 0; c < 10; ++c)
      acc += W[2400 + o * 20 + c] * msg[c] + W[2400 + o * 20 + 10 + c] * rh[c];
    // tanh(x) = 1 - 2/(exp(2x)+1), inline, saturating
    float ex = __expf(2.f * acc);
    float cd = 1.f - 2.f / (ex + 1.f);
    float z = 1.f / (1.f + __expf(-g20[10 + o]));
    float res = (1.f - z) * xpi[o] + z * cd;
    out[((size_t)n * 60 + node * 10 + o) * 3600 + hw] = res;
    if ((o & 3) == 3) fence();
  }
}

// ---------------- launcher -------------------------------------------------
extern "C" void kernel_launch(void* const* d_in, const int* in_sizes, int n_in,
                              void* d_out, int out_size, void* d_ws, size_t ws_size,
                              hipStream_t stream) {
  const float* xh0 = (const float*)d_in[1];
  const float* xh1 = (const float*)d_in[2];
  const float* xp0 = (const float*)d_in[3];
  const float* xp1 = (const float*)d_in[4];
  const float* xp2 = (const float*)d_in[5];
  const float* xp3 = (const float*)d_in[6];
  const float* xp4 = (const float*)d_in[7];
  const float* xp5 = (const float*)d_in[8];
  const float* xp  = (const float*)d_in[9];
  const float* p1w = (const float*)d_in[10];
  const float* p1g = (const float*)d_in[11];
  const float* p1b = (const float*)d_in[12];
  const float* p2w = (const float*)d_in[13];
  const float* p2g = (const float*)d_in[14];
  const float* p2b = (const float*)d_in[15];
  const float* attw = (const float*)d_in[16];
  const float* attb = (const float*)d_in[17];
  const float* ctxw = (const float*)d_in[18];
  const float* ctxb = (const float*)d_in[19];
  const float* duw = (const float*)d_in[20];
  const float* dub = (const float*)d_in[21];
  const float* dlw = (const float*)d_in[22];
  const float* dlb = (const float*)d_in[23];
  const float* c1w = (const float*)d_in[24];
  const float* c1g = (const float*)d_in[25];
  const float* c1b = (const float*)d_in[26];
  const float* c2w = (const float*)d_in[27];
  const float* c2g = (const float*)d_in[28];
  const float* c2b = (const float*)d_in[29];
  const float* gw  = (const float*)d_in[30];
  const float* gb  = (const float*)d_in[31];
  const float* cw  = (const float*)d_in[32];
  const float* cb  = (const float*)d_in[33];

  // Workspace layout (bytes) — total 20,699,136 B (~19.7 MB):
  char* wsb = (char*)d_ws;
  short* w1p   = (short*)(wsb);              //    786,432 B
  short* w2p   = (short*)(wsb + 786432);     //     98,304 B
  short* ctxb2 = (short*)(wsb + 884736);     // 13,824,000 B (bf16 ctx [120][57600])
  float* ws_att = (float*)(wsb + 14708736);  //  4,147,200 B
  float* ws_pu  = (float*)(wsb + 18855936);  //  1,152,000 B
  float* ws_pl  = (float*)(wsb + 20007936);  //    691,200 B
  float* out = (float*)d_out;

  k0_prep<<<216, 256, 0, stream>>>(p1w, p2w, w1p, w2p);
  k1_proj<<<1200, 256, 0, stream>>>(xp, w1p, p1g, p1b, w2p, p2g, p2b, ctxb2);
  k2_att<<<dim3(225, 6), 256, 0, stream>>>(ctxb2, attw, attb, ctxw, ctxb, ws_att, out);
  k3_gates<<<dim3(225, 2), 256, 0, stream>>>(xh0, xh1, duw, dub, dlw, dlb, ws_pu, ws_pl, out);
  k4_node<<<dim3(225, 6), 256, 0, stream>>>(xh0, xh1, xp0, xp1, xp2, xp3, xp4, xp5,
      ws_pu, ws_pl, ws_att, ctxb2,
      c1w, c1g, c1b, c2w, c2g, c2b, gw, gb, cw, cb, out);
}